// Round 5
// baseline (175.000 us; speedup 1.0000x reference)
//
#include <hip/hip_runtime.h>
#include <cstdint>
#include <cstddef>

typedef unsigned short u16;
typedef __bf16 bf16;
typedef bf16 __attribute__((ext_vector_type(4))) bf16x4;
typedef bf16 __attribute__((ext_vector_type(8))) bf16x8;
typedef float __attribute__((ext_vector_type(4))) f32x4;
typedef u16 __attribute__((ext_vector_type(8))) u16x8;

// SCALE * log2(e) folded into Q so softmax runs in exp2 domain
#define QSCALE 0.18033688011112042f

__device__ __forceinline__ u16 f2b(float x) {
  unsigned u = __float_as_uint(x);
  unsigned r = (u + 0x7fffu + ((u >> 16) & 1u)) >> 16;   // RNE
  return (u16)r;
}

__device__ __forceinline__ void gl_lds16(const void* g, void* lds) {
  __builtin_amdgcn_global_load_lds(
      (const __attribute__((address_space(1))) unsigned int*)g,
      (__attribute__((address_space(3))) unsigned int*)lds, 16, 0, 0);
}

// ---- BK=64 tiles ([rows][64], (row&7) chunk-XOR swizzle) --------------------
__device__ __forceinline__ bf16x8 frag(const u16* base, int row, int kchunk) {
  const int c = kchunk ^ (row & 7);
  return *(const bf16x8*)(base + row * 64 + c * 8);
}
__device__ __forceinline__ void stage_tile4(const u16* gbase, int K, char* lbase,
                                            int wave, int lane) {
#pragma unroll
  for (int i = 0; i < 4; ++i) {
    const int q = wave * 64 + lane + i * 256;
    const int r = q >> 3, c = (q & 7) ^ (r & 7);
    gl_lds16(gbase + (size_t)r * K + c * 8, lbase + i * 4096 + wave * 1024);
  }
}

// ---- BK=32 tiles ([rows][32], ((row>>1)&3) chunk-XOR swizzle; 2-way = free) -
__device__ __forceinline__ bf16x8 frag32(const u16* base, int row, int kchunk) {
  const int c = kchunk ^ ((row >> 1) & 3);
  return *(const bf16x8*)(base + row * 32 + c * 8);
}
__device__ __forceinline__ void stage32(const u16* gbase, int K, char* lbase,
                                        int wave, int lane) {
  const int q0 = wave * 64 + lane;                   // 128x32 = 512 chunks of 16B
  const int r0 = q0 >> 2, c0 = (q0 & 3) ^ ((r0 >> 1) & 3);
  gl_lds16(gbase + (size_t)r0 * K + c0 * 8, lbase + wave * 1024);
  const int q1 = q0 + 256;
  const int r1 = q1 >> 2, c1 = (q1 & 3) ^ ((r1 >> 1) & 3);
  gl_lds16(gbase + (size_t)r1 * K + c1 * 8, lbase + 4096 + wave * 1024);
}

// ---------------- cast fp32 -> bf16 (vectorized) ----------------
__global__ __launch_bounds__(256) void castk(const float* __restrict__ in,
                                             u16* __restrict__ out, int n) {
  int i = (blockIdx.x * 256 + threadIdx.x) * 8;
  if (i >= n) return;
  float4 a = *(const float4*)(in + i);
  float4 b = *(const float4*)(in + i + 4);
  u16x8 v;
  v[0] = f2b(a.x); v[1] = f2b(a.y); v[2] = f2b(a.z); v[3] = f2b(a.w);
  v[4] = f2b(b.x); v[5] = f2b(b.y); v[6] = f2b(b.z); v[7] = f2b(b.w);
  *(u16x8*)(out + i) = v;
}

// ---------------- GEMM1: 128x128, BK=32, dbuf, 1 sync/iter, 4 blocks/CU ------
// qkv = X(8192x1024) @ Wqkv(3072x1024)^T, scatter epilogue -> Q(scaled)/K/V^T.
// 32KB LDS + VGPR<=128 -> 4 blocks/CU (16 waves) for latency-filling TLP.
__global__ __launch_bounds__(256, 4) void gemm_qkv(
    const u16* __restrict__ A, const u16* __restrict__ B,
    u16* __restrict__ Qo, u16* __restrict__ Ko, u16* __restrict__ Vo) {
  __shared__ u16 As[2][128 * 32];
  __shared__ u16 Bs[2][128 * 32];
  const int tid = threadIdx.x;
  const int lane = tid & 63, wave = tid >> 6;
  const int fr = lane & 15, fg = lane >> 4;
  const int wr = wave >> 1, wc = wave & 1;
  const int bid = blockIdx.x;
  const int bm = bid & 63, bn = bid >> 6;
  const int K = 1024;
  const u16* Ab = A + (size_t)bm * 128 * K;
  const u16* Bb = B + (size_t)bn * 128 * K;

  f32x4 acc[4][4] = {};

  stage32(Ab, K, (char*)&As[0][0], wave, lane);
  stage32(Bb, K, (char*)&Bs[0][0], wave, lane);
  __syncthreads();

  int cur = 0;
#pragma unroll 1
  for (int t = 0; t < 32; ++t) {
    if (t < 31) {   // prefetch next K-tile; lands during compute(t)
      stage32(Ab + (size_t)(t + 1) * 32, K, (char*)&As[cur ^ 1][0], wave, lane);
      stage32(Bb + (size_t)(t + 1) * 32, K, (char*)&Bs[cur ^ 1][0], wave, lane);
    }
    bf16x8 af[4], bfv[4];
#pragma unroll
    for (int mi = 0; mi < 4; ++mi)
      af[mi] = frag32(&As[cur][0], wr * 64 + mi * 16 + fr, fg);
#pragma unroll
    for (int ni = 0; ni < 4; ++ni)
      bfv[ni] = frag32(&Bs[cur][0], wc * 64 + ni * 16 + fr, fg);
#pragma unroll
    for (int mi = 0; mi < 4; ++mi)
#pragma unroll
      for (int ni = 0; ni < 4; ++ni)
        acc[mi][ni] = __builtin_amdgcn_mfma_f32_16x16x32_bf16(
            af[mi], bfv[ni], acc[mi][ni], 0, 0, 0);
    __syncthreads();   // drains prefetch vmem + lgkm; all waves done with buf
    cur ^= 1;
  }

  // --- scatter epilogue: Q(scaled) / K / V^T ---
  const int gr0 = bm * 128 + wr * 64;
  const int gc0 = bn * 128 + wc * 64;
#pragma unroll
  for (int mi = 0; mi < 4; ++mi) {
    const int rb = gr0 + mi * 16 + fg * 4;
    const int b = rb >> 10, t = rb & 1023;
#pragma unroll
    for (int ni = 0; ni < 4; ++ni) {
      const int c = gc0 + ni * 16 + fr;
      const int region = c >> 10, cc = c & 1023;
      const int h = cc >> 6, d = cc & 63;
      const size_t bh = (size_t)(b * 16 + h);
      if (region == 0) {
#pragma unroll
        for (int g = 0; g < 4; ++g)
          Qo[(bh * 1024 + t + g) * 64 + d] = f2b(acc[mi][ni][g] * QSCALE);
      } else if (region == 1) {
#pragma unroll
        for (int g = 0; g < 4; ++g)
          Ko[(bh * 1024 + t + g) * 64 + d] = f2b(acc[mi][ni][g]);
      } else {
        ushort4 pv;
        pv.x = f2b(acc[mi][ni][0]);
        pv.y = f2b(acc[mi][ni][1]);
        pv.z = f2b(acc[mi][ni][2]);
        pv.w = f2b(acc[mi][ni][3]);
        *(ushort4*)(Vo + (bh * 64 + d) * 1024 + t) = pv;   // V^T: [bh][d][t]
      }
    }
  }
}

// ---------------- GEMM2: 128x128, BK=64, dbuf, 1 sync/iter, swizzled --------
// out = (O @ Wout^T + bias) * msk ; fp32 out.  Grid 512 caps at 2 blocks/CU,
// so keep the bigger BK (more compute per stall window).
__global__ __launch_bounds__(256) void gemm_bt2(
    const u16* __restrict__ A, const u16* __restrict__ B,
    float* __restrict__ Co, const float* __restrict__ bias,
    const float* __restrict__ msk) {
  __shared__ u16 As[2][128 * 64];
  __shared__ u16 Bs[2][128 * 64];
  const int tid = threadIdx.x;
  const int lane = tid & 63, wave = tid >> 6;
  const int fr = lane & 15, fg = lane >> 4;
  const int wr = wave >> 1, wc = wave & 1;
  const int bid = blockIdx.x;
  const int bm = bid & 63, bn = bid >> 6;
  const int K = 1024, N = 1024;
  const u16* Ab = A + (size_t)bm * 128 * K;
  const u16* Bb = B + (size_t)bn * 128 * K;

  f32x4 acc[4][4] = {};

  stage_tile4(Ab, K, (char*)&As[0][0], wave, lane);
  stage_tile4(Bb, K, (char*)&Bs[0][0], wave, lane);
  __syncthreads();

  int cur = 0;
#pragma unroll 1
  for (int t = 0; t < 16; ++t) {
    if (t < 15) {
      stage_tile4(Ab + (size_t)(t + 1) * 64, K, (char*)&As[cur ^ 1][0], wave, lane);
      stage_tile4(Bb + (size_t)(t + 1) * 64, K, (char*)&Bs[cur ^ 1][0], wave, lane);
    }
    bf16x8 af[4][2], bfv[4][2];
#pragma unroll
    for (int mi = 0; mi < 4; ++mi)
#pragma unroll
      for (int kk = 0; kk < 2; ++kk)
        af[mi][kk] = frag(&As[cur][0], wr * 64 + mi * 16 + fr, kk * 4 + fg);
#pragma unroll
    for (int ni = 0; ni < 4; ++ni)
#pragma unroll
      for (int kk = 0; kk < 2; ++kk)
        bfv[ni][kk] = frag(&Bs[cur][0], wc * 64 + ni * 16 + fr, kk * 4 + fg);
#pragma unroll
    for (int mi = 0; mi < 4; ++mi)
#pragma unroll
      for (int ni = 0; ni < 4; ++ni)
#pragma unroll
        for (int kk = 0; kk < 2; ++kk)
          acc[mi][ni] = __builtin_amdgcn_mfma_f32_16x16x32_bf16(
              af[mi][kk], bfv[ni][kk], acc[mi][ni], 0, 0, 0);
    __syncthreads();
    cur ^= 1;
  }

  const int gr0 = bm * 128 + wr * 64;
  const int gc0 = bn * 128 + wc * 64;
#pragma unroll
  for (int mi = 0; mi < 4; ++mi) {
    const int rb = gr0 + mi * 16 + fg * 4;
#pragma unroll
    for (int ni = 0; ni < 4; ++ni) {
      const int c = gc0 + ni * 16 + fr;
      const float bo = bias[c];
#pragma unroll
      for (int g = 0; g < 4; ++g) {
        const int r = rb + g;
        Co[(size_t)r * N + c] = (acc[mi][ni][g] + bo) * msk[r];
      }
    }
  }
}

// ---------------- causal flash attention: dbuf K/V, 1 sync/iter -------------
__global__ __launch_bounds__(256) void attnk(const u16* __restrict__ Qb,
                                             const u16* __restrict__ Kb,
                                             const u16* __restrict__ Vtb,
                                             const float* __restrict__ msk,
                                             u16* __restrict__ Ob) {
  __shared__ u16 Ks[2][64 * 64];     // [t][d], XOR-swizzled via staged source
  __shared__ u16 Vs[2][64 * 64];     // [d][t], XOR-swizzled via staged source
  __shared__ u16 Ps[4][32 * 72];     // per-wave P tile [q][k], stride 72
  const int tid = threadIdx.x;
  const int lane = tid & 63, wave = tid >> 6;
  const int fr = lane & 15, fg = lane >> 4;
  const int bid = blockIdx.x;
  __constant__ static const int tab[8] = {7, 6, 0, 1, 5, 4, 2, 3};
  const int qi = tab[bid >> 7];
  const int bh = bid & 127;
  const int b = bh >> 4, h = bh & 15;
  const int qw = qi * 128 + wave * 32;

  bf16x8 qf[2][2];
#pragma unroll
  for (int ct = 0; ct < 2; ++ct)
#pragma unroll
    for (int kc = 0; kc < 2; ++kc)
      qf[ct][kc] = *(const bf16x8*)(Qb + ((size_t)bh * 1024 + qw + ct * 16 + fr) * 64 +
                                    kc * 32 + fg * 8);

  f32x4 o[2][4] = {};
  float mrun[2], lrun[2];
  mrun[0] = mrun[1] = -3.0e38f;
  lrun[0] = lrun[1] = 0.f;

  const int cc0 = wave * 64 + lane;
  const int krow0 = cc0 >> 3, kcb0 = (cc0 & 7) ^ (krow0 & 7);
  const int cc1 = 256 + cc0;
  const int krow1 = cc1 >> 3, kcb1 = (cc1 & 7) ^ (krow1 & 7);

  const int nkb = qi * 2 + 2;

  // prologue: stage kb=0 into buf 0
  gl_lds16(Kb + ((size_t)bh * 1024 + krow0) * 64 + kcb0 * 8, (char*)&Ks[0][0] + wave * 1024);
  gl_lds16(Vtb + ((size_t)bh * 64 + krow0) * 1024 + kcb0 * 8, (char*)&Vs[0][0] + wave * 1024);
  gl_lds16(Kb + ((size_t)bh * 1024 + krow1) * 64 + kcb1 * 8, (char*)&Ks[0][0] + 4096 + wave * 1024);
  gl_lds16(Vtb + ((size_t)bh * 64 + krow1) * 1024 + kcb1 * 8, (char*)&Vs[0][0] + 4096 + wave * 1024);

#pragma unroll 1
  for (int kb = 0; kb < nkb; ++kb) {
    __syncthreads();   // stage(kb) landed (implicit vmcnt0); compute(kb-1) done
    if (kb + 1 < nkb) {   // prefetch kb+1 into other buffer; hides under compute
      char* kd = (char*)&Ks[(kb + 1) & 1][0];
      char* vd = (char*)&Vs[(kb + 1) & 1][0];
      gl_lds16(Kb + ((size_t)bh * 1024 + (kb + 1) * 64 + krow0) * 64 + kcb0 * 8, kd + wave * 1024);
      gl_lds16(Vtb + ((size_t)bh * 64 + krow0) * 1024 + (kb + 1) * 64 + kcb0 * 8, vd + wave * 1024);
      gl_lds16(Kb + ((size_t)bh * 1024 + (kb + 1) * 64 + krow1) * 64 + kcb1 * 8, kd + 4096 + wave * 1024);
      gl_lds16(Vtb + ((size_t)bh * 64 + krow1) * 1024 + (kb + 1) * 64 + kcb1 * 8, vd + 4096 + wave * 1024);
    }
    if (kb * 64 > qw + 31) continue;  // fully masked for this wave (sync count uniform)
    const u16* Kc = &Ks[kb & 1][0];
    const u16* Vc = &Vs[kb & 1][0];

    // --- S^T = K * Q^T : lane owns q-col = ct*16+fr, rows k = nt*16+fg*4+g ---
    f32x4 st[2][4];                  // [ct][nt]
    const f32x4 z = {0.f, 0.f, 0.f, 0.f};
#pragma unroll
    for (int nt = 0; nt < 4; ++nt) {
      const int krow = nt * 16 + fr;
      const int cb0r = (0 * 4 + fg) ^ (krow & 7);
      const int cb1r = (1 * 4 + fg) ^ (krow & 7);
      const bf16x8 kf0 = *(const bf16x8*)(Kc + krow * 64 + cb0r * 8);
      const bf16x8 kf1 = *(const bf16x8*)(Kc + krow * 64 + cb1r * 8);
#pragma unroll
      for (int ct = 0; ct < 2; ++ct) {
        st[ct][nt] = __builtin_amdgcn_mfma_f32_16x16x32_bf16(kf0, qf[ct][0], z, 0, 0, 0);
        st[ct][nt] = __builtin_amdgcn_mfma_f32_16x16x32_bf16(kf1, qf[ct][1], st[ct][nt], 0, 0, 0);
      }
    }

    // --- key padding mask (additive bias) ---
    float kbias[4][4];
#pragma unroll
    for (int nt = 0; nt < 4; ++nt) {
      const float4 km4 = *(const float4*)(msk + b * 1024 + kb * 64 + nt * 16 + fg * 4);
      kbias[nt][0] = (km4.x == 0.f) ? -3.0e38f : 0.f;
      kbias[nt][1] = (km4.y == 0.f) ? -3.0e38f : 0.f;
      kbias[nt][2] = (km4.z == 0.f) ? -3.0e38f : 0.f;
      kbias[nt][3] = (km4.w == 0.f) ? -3.0e38f : 0.f;
    }
#pragma unroll
    for (int ct = 0; ct < 2; ++ct)
#pragma unroll
      for (int nt = 0; nt < 4; ++nt)
#pragma unroll
        for (int g = 0; g < 4; ++g) st[ct][nt][g] += kbias[nt][g];

    // --- causal mask (diagonal tiles only) ---
    const bool edge = (kb * 64 + 63 > qw);
    if (edge) {
#pragma unroll
      for (int ct = 0; ct < 2; ++ct) {
        const int q = qw + ct * 16 + fr;
#pragma unroll
        for (int nt = 0; nt < 4; ++nt)
#pragma unroll
          for (int g = 0; g < 4; ++g) {
            const int j = kb * 64 + nt * 16 + fg * 4 + g;
            if (j > q) st[ct][nt][g] = -3.0e38f;
          }
      }
    }

    // --- online softmax: in-lane over 16 + 2 shfl_xor (cross-fg) ---
    float sc[2];
#pragma unroll
    for (int ct = 0; ct < 2; ++ct) {
      float mx = st[ct][0][0];
#pragma unroll
      for (int nt = 0; nt < 4; ++nt)
#pragma unroll
        for (int g = 0; g < 4; ++g) mx = fmaxf(mx, st[ct][nt][g]);
      mx = fmaxf(mx, __shfl_xor(mx, 16));
      mx = fmaxf(mx, __shfl_xor(mx, 32));
      const float nm = fmaxf(mrun[ct], mx);
      sc[ct] = exp2f(mrun[ct] - nm);
      mrun[ct] = nm;
      float rs = 0.f;
#pragma unroll
      for (int nt = 0; nt < 4; ++nt)
#pragma unroll
        for (int g = 0; g < 4; ++g) {
          const float p = exp2f(st[ct][nt][g] - nm);
          st[ct][nt][g] = p;
          rs += p;
        }
      rs += __shfl_xor(rs, 16);
      rs += __shfl_xor(rs, 32);
      lrun[ct] = lrun[ct] * sc[ct] + rs;
      // packed P write: row q = ct*16+fr, cols nt*16+fg*4..+3 (8B store)
#pragma unroll
      for (int nt = 0; nt < 4; ++nt) {
        bf16x4 pk;
        pk[0] = (bf16)st[ct][nt][0];
        pk[1] = (bf16)st[ct][nt][1];
        pk[2] = (bf16)st[ct][nt][2];
        pk[3] = (bf16)st[ct][nt][3];
        *(bf16x4*)(&Ps[wave][(ct * 16 + fr) * 72 + nt * 16 + fg * 4]) = pk;
      }
    }

    // --- rescale O (O rows live at q = mt*16 + fg*4 + g, sc lives at fr=q) ---
#pragma unroll
    for (int mt = 0; mt < 2; ++mt)
#pragma unroll
      for (int g = 0; g < 4; ++g) {
        const float scr = __shfl(sc[mt], fg * 4 + g);
#pragma unroll
        for (int dt = 0; dt < 4; ++dt) o[mt][dt][g] *= scr;
      }

    // --- PV: O[q][d] += P[q][k] * V[k][d] ---
#pragma unroll
    for (int jc = 0; jc < 2; ++jc) {
      bf16x8 pa[2];
#pragma unroll
      for (int mt = 0; mt < 2; ++mt)
        pa[mt] = *(const bf16x8*)(&Ps[wave][(mt * 16 + fr) * 72 + jc * 32 + fg * 8]);
#pragma unroll
      for (int dt = 0; dt < 4; ++dt) {
        const int vrow = dt * 16 + fr;
        const int cb = (jc * 4 + fg) ^ (vrow & 7);
        const bf16x8 vf = *(const bf16x8*)(Vc + vrow * 64 + cb * 8);
#pragma unroll
        for (int mt = 0; mt < 2; ++mt)
          o[mt][dt] = __builtin_amdgcn_mfma_f32_16x16x32_bf16(pa[mt], vf, o[mt][dt], 0, 0, 0);
      }
    }
  }

  // --- epilogue: O / l -> Ob[b][t][h*64+d] (bf16) ---
  float inv[2];
  inv[0] = 1.0f / lrun[0];
  inv[1] = 1.0f / lrun[1];
#pragma unroll
  for (int mt = 0; mt < 2; ++mt)
#pragma unroll
    for (int g = 0; g < 4; ++g) {
      const float invr = __shfl(inv[mt], fg * 4 + g);
      const int q = qw + mt * 16 + fg * 4 + g;
#pragma unroll
      for (int dt = 0; dt < 4; ++dt)
        Ob[((size_t)b * 1024 + q) * 1024 + h * 64 + dt * 16 + fr] =
            f2b(o[mt][dt][g] * invr);
    }
}

// ---------------- launcher ----------------
extern "C" void kernel_launch(void* const* d_in, const int* in_sizes, int n_in,
                              void* d_out, int out_size, void* d_ws, size_t ws_size,
                              hipStream_t stream) {
  (void)in_sizes; (void)n_in; (void)out_size; (void)ws_size;
  const float* x = (const float*)d_in[0];
  const float* m = (const float*)d_in[1];
  const float* w_qkv = (const float*)d_in[2];
  const float* w_out = (const float*)d_in[3];
  const float* b_out = (const float*)d_in[4];
  float* out = (float*)d_out;

  char* ws = (char*)d_ws;
  const size_t MB = 1u << 20;
  u16* Xb    = (u16*)(ws + 0);         // 16MB, reused as Ob after GEMM1
  u16* Wqkvb = (u16*)(ws + 16 * MB);   // 6MB
  u16* Woutb = (u16*)(ws + 22 * MB);   // 2MB
  u16* Qb    = (u16*)(ws + 24 * MB);   // 16MB
  u16* Kb    = (u16*)(ws + 40 * MB);   // 16MB
  u16* Vtb   = (u16*)(ws + 56 * MB);   // 16MB  -> total 72MB
  u16* Ob    = Xb;                      // alias: X dead after GEMM1

  // casts
  castk<<<4096, 256, 0, stream>>>(x, Xb, 8 * 1024 * 1024);
  castk<<<1536, 256, 0, stream>>>(w_qkv, Wqkvb, 3072 * 1024);
  castk<<<512, 256, 0, stream>>>(w_out, Woutb, 1024 * 1024);

  // GEMM1: qkv = X @ Wqkv^T (128^2, BK=32 dbuf, 4 blocks/CU TLP)
  gemm_qkv<<<1536, 256, 0, stream>>>(Xb, Wqkvb, Qb, Kb, Vtb);

  // flash attention (dbuf K/V, 1 sync per K-tile)
  attnk<<<1024, 256, 0, stream>>>(Qb, Kb, Vtb, m, Ob);

  // GEMM2: out = (O @ Wout^T + b_out) * m  (128^2, BK=64 dbuf)
  gemm_bt2<<<512, 256, 0, stream>>>(Ob, Woutb, out, b_out, m);
}

// Round 6
// 170.922 us; speedup vs baseline: 1.0239x; 1.0239x over previous
//
#include <hip/hip_runtime.h>
#include <cstdint>
#include <cstddef>

typedef unsigned short u16;
typedef __bf16 bf16;
typedef bf16 __attribute__((ext_vector_type(2))) bf16x2;
typedef bf16 __attribute__((ext_vector_type(4))) bf16x4;
typedef bf16 __attribute__((ext_vector_type(8))) bf16x8;
typedef float __attribute__((ext_vector_type(4))) f32x4;
typedef u16 __attribute__((ext_vector_type(8))) u16x8;

// SCALE * log2(e) folded into Q so softmax runs in exp2 domain
#define QSCALE 0.18033688011112042f

__device__ __forceinline__ u16 f2b(float x) {
  unsigned u = __float_as_uint(x);
  unsigned r = (u + 0x7fffu + ((u >> 16) & 1u)) >> 16;   // RNE
  return (u16)r;
}

__device__ __forceinline__ void gl_lds16(const void* g, void* lds) {
  __builtin_amdgcn_global_load_lds(
      (const __attribute__((address_space(1))) unsigned int*)g,
      (__attribute__((address_space(3))) unsigned int*)lds, 16, 0, 0);
}

// ---- BK=64 tiles ([rows][64], (row&7) chunk-XOR swizzle) --------------------
__device__ __forceinline__ bf16x8 frag(const u16* base, int row, int kchunk) {
  const int c = kchunk ^ (row & 7);
  return *(const bf16x8*)(base + row * 64 + c * 8);
}
__device__ __forceinline__ void stage_tile4(const u16* gbase, int K, char* lbase,
                                            int wave, int lane) {
#pragma unroll
  for (int i = 0; i < 4; ++i) {
    const int q = wave * 64 + lane + i * 256;
    const int r = q >> 3, c = (q & 7) ^ (r & 7);
    gl_lds16(gbase + (size_t)r * K + c * 8, lbase + i * 4096 + wave * 1024);
  }
}

// ---- BK=32 tiles ([rows][32], ((row>>1)&3) chunk-XOR swizzle; 2-way = free) -
__device__ __forceinline__ bf16x8 frag32(const u16* base, int row, int kchunk) {
  const int c = kchunk ^ ((row >> 1) & 3);
  return *(const bf16x8*)(base + row * 32 + c * 8);
}
__device__ __forceinline__ void stage32(const u16* gbase, int K, char* lbase,
                                        int wave, int lane) {
  const int q0 = wave * 64 + lane;                   // 128x32 = 512 chunks of 16B
  const int r0 = q0 >> 2, c0 = (q0 & 3) ^ ((r0 >> 1) & 3);
  gl_lds16(gbase + (size_t)r0 * K + c0 * 8, lbase + wave * 1024);
  const int q1 = q0 + 256;
  const int r1 = q1 >> 2, c1 = (q1 & 3) ^ ((r1 >> 1) & 3);
  gl_lds16(gbase + (size_t)r1 * K + c1 * 8, lbase + 4096 + wave * 1024);
}

// ---------------- cast fp32 -> bf16 (vectorized) ----------------
__global__ __launch_bounds__(256) void castk(const float* __restrict__ in,
                                             u16* __restrict__ out, int n) {
  int i = (blockIdx.x * 256 + threadIdx.x) * 8;
  if (i >= n) return;
  float4 a = *(const float4*)(in + i);
  float4 b = *(const float4*)(in + i + 4);
  u16x8 v;
  v[0] = f2b(a.x); v[1] = f2b(a.y); v[2] = f2b(a.z); v[3] = f2b(a.w);
  v[4] = f2b(b.x); v[5] = f2b(b.y); v[6] = f2b(b.z); v[7] = f2b(b.w);
  *(u16x8*)(out + i) = v;
}

// ---------------- GEMM1: 128x128, BK=32, dbuf, 1 sync/iter, 4 blocks/CU ------
__global__ __launch_bounds__(256, 4) void gemm_qkv(
    const u16* __restrict__ A, const u16* __restrict__ B,
    u16* __restrict__ Qo, u16* __restrict__ Ko, u16* __restrict__ Vo) {
  __shared__ u16 As[2][128 * 32];
  __shared__ u16 Bs[2][128 * 32];
  const int tid = threadIdx.x;
  const int lane = tid & 63, wave = tid >> 6;
  const int fr = lane & 15, fg = lane >> 4;
  const int wr = wave >> 1, wc = wave & 1;
  const int bid = blockIdx.x;
  const int bm = bid & 63, bn = bid >> 6;
  const int K = 1024;
  const u16* Ab = A + (size_t)bm * 128 * K;
  const u16* Bb = B + (size_t)bn * 128 * K;

  f32x4 acc[4][4] = {};

  stage32(Ab, K, (char*)&As[0][0], wave, lane);
  stage32(Bb, K, (char*)&Bs[0][0], wave, lane);
  __syncthreads();

  int cur = 0;
#pragma unroll 1
  for (int t = 0; t < 32; ++t) {
    if (t < 31) {
      stage32(Ab + (size_t)(t + 1) * 32, K, (char*)&As[cur ^ 1][0], wave, lane);
      stage32(Bb + (size_t)(t + 1) * 32, K, (char*)&Bs[cur ^ 1][0], wave, lane);
    }
    bf16x8 af[4], bfv[4];
#pragma unroll
    for (int mi = 0; mi < 4; ++mi)
      af[mi] = frag32(&As[cur][0], wr * 64 + mi * 16 + fr, fg);
#pragma unroll
    for (int ni = 0; ni < 4; ++ni)
      bfv[ni] = frag32(&Bs[cur][0], wc * 64 + ni * 16 + fr, fg);
#pragma unroll
    for (int mi = 0; mi < 4; ++mi)
#pragma unroll
      for (int ni = 0; ni < 4; ++ni)
        acc[mi][ni] = __builtin_amdgcn_mfma_f32_16x16x32_bf16(
            af[mi], bfv[ni], acc[mi][ni], 0, 0, 0);
    __syncthreads();
    cur ^= 1;
  }

  const int gr0 = bm * 128 + wr * 64;
  const int gc0 = bn * 128 + wc * 64;
#pragma unroll
  for (int mi = 0; mi < 4; ++mi) {
    const int rb = gr0 + mi * 16 + fg * 4;
    const int b = rb >> 10, t = rb & 1023;
#pragma unroll
    for (int ni = 0; ni < 4; ++ni) {
      const int c = gc0 + ni * 16 + fr;
      const int region = c >> 10, cc = c & 1023;
      const int h = cc >> 6, d = cc & 63;
      const size_t bh = (size_t)(b * 16 + h);
      if (region == 0) {
#pragma unroll
        for (int g = 0; g < 4; ++g)
          Qo[(bh * 1024 + t + g) * 64 + d] = f2b(acc[mi][ni][g] * QSCALE);
      } else if (region == 1) {
#pragma unroll
        for (int g = 0; g < 4; ++g)
          Ko[(bh * 1024 + t + g) * 64 + d] = f2b(acc[mi][ni][g]);
      } else {
        ushort4 pv;
        pv.x = f2b(acc[mi][ni][0]);
        pv.y = f2b(acc[mi][ni][1]);
        pv.z = f2b(acc[mi][ni][2]);
        pv.w = f2b(acc[mi][ni][3]);
        *(ushort4*)(Vo + (bh * 64 + d) * 1024 + t) = pv;   // V^T: [bh][d][t]
      }
    }
  }
}

// ---------------- GEMM2: 128x128, BK=64, dbuf, 1 sync/iter, swizzled --------
__global__ __launch_bounds__(256) void gemm_bt2(
    const u16* __restrict__ A, const u16* __restrict__ B,
    float* __restrict__ Co, const float* __restrict__ bias,
    const float* __restrict__ msk) {
  __shared__ u16 As[2][128 * 64];
  __shared__ u16 Bs[2][128 * 64];
  const int tid = threadIdx.x;
  const int lane = tid & 63, wave = tid >> 6;
  const int fr = lane & 15, fg = lane >> 4;
  const int wr = wave >> 1, wc = wave & 1;
  const int bid = blockIdx.x;
  const int bm = bid & 63, bn = bid >> 6;
  const int K = 1024, N = 1024;
  const u16* Ab = A + (size_t)bm * 128 * K;
  const u16* Bb = B + (size_t)bn * 128 * K;

  f32x4 acc[4][4] = {};

  stage_tile4(Ab, K, (char*)&As[0][0], wave, lane);
  stage_tile4(Bb, K, (char*)&Bs[0][0], wave, lane);
  __syncthreads();

  int cur = 0;
#pragma unroll 1
  for (int t = 0; t < 16; ++t) {
    if (t < 15) {
      stage_tile4(Ab + (size_t)(t + 1) * 64, K, (char*)&As[cur ^ 1][0], wave, lane);
      stage_tile4(Bb + (size_t)(t + 1) * 64, K, (char*)&Bs[cur ^ 1][0], wave, lane);
    }
    bf16x8 af[4][2], bfv[4][2];
#pragma unroll
    for (int mi = 0; mi < 4; ++mi)
#pragma unroll
      for (int kk = 0; kk < 2; ++kk)
        af[mi][kk] = frag(&As[cur][0], wr * 64 + mi * 16 + fr, kk * 4 + fg);
#pragma unroll
    for (int ni = 0; ni < 4; ++ni)
#pragma unroll
      for (int kk = 0; kk < 2; ++kk)
        bfv[ni][kk] = frag(&Bs[cur][0], wc * 64 + ni * 16 + fr, kk * 4 + fg);
#pragma unroll
    for (int mi = 0; mi < 4; ++mi)
#pragma unroll
      for (int ni = 0; ni < 4; ++ni)
#pragma unroll
        for (int kk = 0; kk < 2; ++kk)
          acc[mi][ni] = __builtin_amdgcn_mfma_f32_16x16x32_bf16(
              af[mi][kk], bfv[ni][kk], acc[mi][ni], 0, 0, 0);
    __syncthreads();
    cur ^= 1;
  }

  const int gr0 = bm * 128 + wr * 64;
  const int gc0 = bn * 128 + wc * 64;
#pragma unroll
  for (int mi = 0; mi < 4; ++mi) {
    const int rb = gr0 + mi * 16 + fg * 4;
#pragma unroll
    for (int ni = 0; ni < 4; ++ni) {
      const int c = gc0 + ni * 16 + fr;
      const float bo = bias[c];
#pragma unroll
      for (int g = 0; g < 4; ++g) {
        const int r = rb + g;
        Co[(size_t)r * N + c] = (acc[mi][ni][g] + bo) * msk[r];
      }
    }
  }
}

// ---------------- causal flash attention: dbuf K/V, in-register P -----------
// LDS 32KB -> 4 blocks/CU; grid 1024 = all blocks co-resident (zero tail).
// P never touches LDS: cvt_pk pairs + ds_bpermute redistribute to PV A-frags.
__global__ __launch_bounds__(256) void attnk(const u16* __restrict__ Qb,
                                             const u16* __restrict__ Kb,
                                             const u16* __restrict__ Vtb,
                                             const float* __restrict__ msk,
                                             u16* __restrict__ Ob) {
  __shared__ u16 Ks[2][64 * 64];     // [t][d], XOR-swizzled via staged source
  __shared__ u16 Vs[2][64 * 64];     // [d][t], XOR-swizzled via staged source
  const int tid = threadIdx.x;
  const int lane = tid & 63, wave = tid >> 6;
  const int fr = lane & 15, fg = lane >> 4;
  const int bid = blockIdx.x;
  __constant__ static const int tab[8] = {7, 6, 0, 1, 5, 4, 2, 3};
  const int qi = tab[bid >> 7];
  const int bh = bid & 127;
  const int b = bh >> 4, h = bh & 15;
  const int qw = qi * 128 + wave * 32;

  bf16x8 qf[2][2];
#pragma unroll
  for (int ct = 0; ct < 2; ++ct)
#pragma unroll
    for (int kc = 0; kc < 2; ++kc)
      qf[ct][kc] = *(const bf16x8*)(Qb + ((size_t)bh * 1024 + qw + ct * 16 + fr) * 64 +
                                    kc * 32 + fg * 8);

  f32x4 o[2][4] = {};
  float mrun[2], lrun[2];
  mrun[0] = mrun[1] = -3.0e38f;
  lrun[0] = lrun[1] = 0.f;

  // bpermute source lanes for P redistribution (derivation in round notes):
  // target lane (fr,fg), word e2 of (mt,jc):
  //   value = pk[mt][jc*2 + (fg>>1)][e2&1] from lane fr + (fg&1)*32 + (e2&2 ? 16:0)
  const int src0 = fr + ((fg & 1) << 5);
  const int src1 = src0 + 16;

  const int cc0 = wave * 64 + lane;
  const int krow0 = cc0 >> 3, kcb0 = (cc0 & 7) ^ (krow0 & 7);
  const int cc1 = 256 + cc0;
  const int krow1 = cc1 >> 3, kcb1 = (cc1 & 7) ^ (krow1 & 7);

  const int nkb = qi * 2 + 2;

  // prologue: stage kb=0 into buf 0
  gl_lds16(Kb + ((size_t)bh * 1024 + krow0) * 64 + kcb0 * 8, (char*)&Ks[0][0] + wave * 1024);
  gl_lds16(Vtb + ((size_t)bh * 64 + krow0) * 1024 + kcb0 * 8, (char*)&Vs[0][0] + wave * 1024);
  gl_lds16(Kb + ((size_t)bh * 1024 + krow1) * 64 + kcb1 * 8, (char*)&Ks[0][0] + 4096 + wave * 1024);
  gl_lds16(Vtb + ((size_t)bh * 64 + krow1) * 1024 + kcb1 * 8, (char*)&Vs[0][0] + 4096 + wave * 1024);

#pragma unroll 1
  for (int kb = 0; kb < nkb; ++kb) {
    __syncthreads();   // stage(kb) landed (implicit vmcnt0); compute(kb-1) done
    if (kb + 1 < nkb) {   // prefetch kb+1; hides under compute
      char* kd = (char*)&Ks[(kb + 1) & 1][0];
      char* vd = (char*)&Vs[(kb + 1) & 1][0];
      gl_lds16(Kb + ((size_t)bh * 1024 + (kb + 1) * 64 + krow0) * 64 + kcb0 * 8, kd + wave * 1024);
      gl_lds16(Vtb + ((size_t)bh * 64 + krow0) * 1024 + (kb + 1) * 64 + kcb0 * 8, vd + wave * 1024);
      gl_lds16(Kb + ((size_t)bh * 1024 + (kb + 1) * 64 + krow1) * 64 + kcb1 * 8, kd + 4096 + wave * 1024);
      gl_lds16(Vtb + ((size_t)bh * 64 + krow1) * 1024 + (kb + 1) * 64 + kcb1 * 8, vd + 4096 + wave * 1024);
    }
    if (kb * 64 > qw + 31) continue;  // fully masked for this wave (sync count uniform)
    const u16* Kc = &Ks[kb & 1][0];
    const u16* Vc = &Vs[kb & 1][0];

    // --- S^T = K * Q^T : lane owns q-col = ct*16+fr, rows k = nt*16+fg*4+g ---
    f32x4 st[2][4];                  // [ct][nt]
    const f32x4 z = {0.f, 0.f, 0.f, 0.f};
#pragma unroll
    for (int nt = 0; nt < 4; ++nt) {
      const int krow = nt * 16 + fr;
      const int cb0r = (0 * 4 + fg) ^ (krow & 7);
      const int cb1r = (1 * 4 + fg) ^ (krow & 7);
      const bf16x8 kf0 = *(const bf16x8*)(Kc + krow * 64 + cb0r * 8);
      const bf16x8 kf1 = *(const bf16x8*)(Kc + krow * 64 + cb1r * 8);
#pragma unroll
      for (int ct = 0; ct < 2; ++ct) {
        st[ct][nt] = __builtin_amdgcn_mfma_f32_16x16x32_bf16(kf0, qf[ct][0], z, 0, 0, 0);
        st[ct][nt] = __builtin_amdgcn_mfma_f32_16x16x32_bf16(kf1, qf[ct][1], st[ct][nt], 0, 0, 0);
      }
    }

    // --- key padding mask values (applied post-exp2 as multiply) ---
    float kmv[4][4];
#pragma unroll
    for (int nt = 0; nt < 4; ++nt) {
      const float4 km4 = *(const float4*)(msk + b * 1024 + kb * 64 + nt * 16 + fg * 4);
      kmv[nt][0] = km4.x; kmv[nt][1] = km4.y; kmv[nt][2] = km4.z; kmv[nt][3] = km4.w;
    }

    // --- causal mask (diagonal tiles only) ---
    const bool edge = (kb * 64 + 63 > qw);
    if (edge) {
#pragma unroll
      for (int ct = 0; ct < 2; ++ct) {
        const int q = qw + ct * 16 + fr;
#pragma unroll
        for (int nt = 0; nt < 4; ++nt)
#pragma unroll
          for (int g = 0; g < 4; ++g) {
            const int j = kb * 64 + nt * 16 + fg * 4 + g;
            if (j > q) st[ct][nt][g] = -3.0e38f;
          }
      }
    }

    // --- online softmax with defer-max (T13, THR=8) ---
    float sc[2];
    int doR[2];
#pragma unroll
    for (int ct = 0; ct < 2; ++ct) {
      float mx = st[ct][0][0];
#pragma unroll
      for (int nt = 0; nt < 4; ++nt)
#pragma unroll
        for (int g = 0; g < 4; ++g) mx = fmaxf(mx, st[ct][nt][g]);
      mx = fmaxf(mx, __shfl_xor(mx, 16));
      mx = fmaxf(mx, __shfl_xor(mx, 32));
      float nm;
      if (__all(mx <= mrun[ct] + 8.f)) {
        nm = mrun[ct]; sc[ct] = 1.f; doR[ct] = 0;
      } else {
        nm = fmaxf(mrun[ct], mx);
        sc[ct] = exp2f(mrun[ct] - nm);
        mrun[ct] = nm; doR[ct] = 1;
      }
      float rs = 0.f;
#pragma unroll
      for (int nt = 0; nt < 4; ++nt)
#pragma unroll
        for (int g = 0; g < 4; ++g) {
          const float p = exp2f(st[ct][nt][g] - nm) * kmv[nt][g];
          st[ct][nt][g] = p;
          rs += p;
        }
      rs += __shfl_xor(rs, 16);
      rs += __shfl_xor(rs, 32);
      lrun[ct] = doR[ct] ? (lrun[ct] * sc[ct] + rs) : (lrun[ct] + rs);
    }

    // --- pack P pairs to bf16x2 words (compiler emits v_cvt_pk_bf16_f32) ---
    int pk[2][4][2];
#pragma unroll
    for (int ct = 0; ct < 2; ++ct)
#pragma unroll
      for (int nt = 0; nt < 4; ++nt)
#pragma unroll
        for (int hh = 0; hh < 2; ++hh) {
          bf16x2 tp;
          tp[0] = (bf16)st[ct][nt][2 * hh];
          tp[1] = (bf16)st[ct][nt][2 * hh + 1];
          pk[ct][nt][hh] = __builtin_bit_cast(int, tp);
        }

    // --- redistribute to PV A-fragments via bpermute (no LDS) ---
    bf16x8 pa[2][2];
#pragma unroll
    for (int mt = 0; mt < 2; ++mt)
#pragma unroll
      for (int jc = 0; jc < 2; ++jc) {
        int w[4];
#pragma unroll
        for (int e2 = 0; e2 < 4; ++e2) {
          const int sl = (e2 & 2) ? src1 : src0;
          const int lo = __shfl(pk[mt][jc * 2 + 0][e2 & 1], sl);
          const int hi = __shfl(pk[mt][jc * 2 + 1][e2 & 1], sl);
          w[e2] = (fg & 2) ? hi : lo;
        }
        int4 wi = {w[0], w[1], w[2], w[3]};
        pa[mt][jc] = __builtin_bit_cast(bf16x8, wi);
      }

    // --- rescale O only when max grew (wave-uniform branch) ---
#pragma unroll
    for (int mt = 0; mt < 2; ++mt)
      if (doR[mt]) {
#pragma unroll
        for (int g = 0; g < 4; ++g) {
          const float scr = __shfl(sc[mt], fg * 4 + g);
#pragma unroll
          for (int dt = 0; dt < 4; ++dt) o[mt][dt][g] *= scr;
        }
      }

    // --- PV: O[q][d] += P[q][k] * V[k][d] ---
#pragma unroll
    for (int jc = 0; jc < 2; ++jc)
#pragma unroll
      for (int dt = 0; dt < 4; ++dt) {
        const int vrow = dt * 16 + fr;
        const int cb = (jc * 4 + fg) ^ (vrow & 7);
        const bf16x8 vf = *(const bf16x8*)(Vc + vrow * 64 + cb * 8);
#pragma unroll
        for (int mt = 0; mt < 2; ++mt)
          o[mt][dt] = __builtin_amdgcn_mfma_f32_16x16x32_bf16(pa[mt][jc], vf, o[mt][dt], 0, 0, 0);
      }
  }

  // --- epilogue: O / l -> Ob[b][t][h*64+d] (bf16) ---
  float inv[2];
  inv[0] = 1.0f / lrun[0];
  inv[1] = 1.0f / lrun[1];
#pragma unroll
  for (int mt = 0; mt < 2; ++mt)
#pragma unroll
    for (int g = 0; g < 4; ++g) {
      const float invr = __shfl(inv[mt], fg * 4 + g);
      const int q = qw + mt * 16 + fg * 4 + g;
#pragma unroll
      for (int dt = 0; dt < 4; ++dt)
        Ob[((size_t)b * 1024 + q) * 1024 + h * 64 + dt * 16 + fr] =
            f2b(o[mt][dt][g] * invr);
    }
}

// ---------------- launcher ----------------
extern "C" void kernel_launch(void* const* d_in, const int* in_sizes, int n_in,
                              void* d_out, int out_size, void* d_ws, size_t ws_size,
                              hipStream_t stream) {
  (void)in_sizes; (void)n_in; (void)out_size; (void)ws_size;
  const float* x = (const float*)d_in[0];
  const float* m = (const float*)d_in[1];
  const float* w_qkv = (const float*)d_in[2];
  const float* w_out = (const float*)d_in[3];
  const float* b_out = (const float*)d_in[4];
  float* out = (float*)d_out;

  char* ws = (char*)d_ws;
  const size_t MB = 1u << 20;
  u16* Xb    = (u16*)(ws + 0);         // 16MB, reused as Ob after GEMM1
  u16* Wqkvb = (u16*)(ws + 16 * MB);   // 6MB
  u16* Woutb = (u16*)(ws + 22 * MB);   // 2MB
  u16* Qb    = (u16*)(ws + 24 * MB);   // 16MB
  u16* Kb    = (u16*)(ws + 40 * MB);   // 16MB
  u16* Vtb   = (u16*)(ws + 56 * MB);   // 16MB  -> total 72MB
  u16* Ob    = Xb;                      // alias: X dead after GEMM1

  // casts
  castk<<<4096, 256, 0, stream>>>(x, Xb, 8 * 1024 * 1024);
  castk<<<1536, 256, 0, stream>>>(w_qkv, Wqkvb, 3072 * 1024);
  castk<<<512, 256, 0, stream>>>(w_out, Woutb, 1024 * 1024);

  // GEMM1: qkv = X @ Wqkv^T (128^2, BK=32 dbuf, 4 blocks/CU TLP)
  gemm_qkv<<<1536, 256, 0, stream>>>(Xb, Wqkvb, Qb, Kb, Vtb);

  // flash attention (dbuf K/V, in-register P, 4 blocks/CU co-resident)
  attnk<<<1024, 256, 0, stream>>>(Qb, Kb, Vtb, m, Ob);

  // GEMM2: out = (O @ Wout^T + b_out) * m  (128^2, BK=64 dbuf)
  gemm_bt2<<<512, 256, 0, stream>>>(Ob, Woutb, out, b_out, m);
}

// Round 7
// 166.521 us; speedup vs baseline: 1.0509x; 1.0264x over previous
//
#include <hip/hip_runtime.h>
#include <cstdint>
#include <cstddef>

typedef unsigned short u16;
typedef __bf16 bf16;
typedef bf16 __attribute__((ext_vector_type(2))) bf16x2;
typedef bf16 __attribute__((ext_vector_type(8))) bf16x8;
typedef float __attribute__((ext_vector_type(4))) f32x4;
typedef u16 __attribute__((ext_vector_type(8))) u16x8;

// SCALE * log2(e) folded into Q so softmax runs in exp2 domain
#define QSCALE 0.18033688011112042f

__device__ __forceinline__ u16 f2b(float x) {
  unsigned u = __float_as_uint(x);
  unsigned r = (u + 0x7fffu + ((u >> 16) & 1u)) >> 16;   // RNE
  return (u16)r;
}

__device__ __forceinline__ void gl_lds16(const void* g, void* lds) {
  __builtin_amdgcn_global_load_lds(
      (const __attribute__((address_space(1))) unsigned int*)g,
      (__attribute__((address_space(3))) unsigned int*)lds, 16, 0, 0);
}

// ---- BK=64 tiles ([rows][64], (row&7) chunk-XOR swizzle) --------------------
__device__ __forceinline__ bf16x8 frag(const u16* base, int row, int kchunk) {
  const int c = kchunk ^ (row & 7);
  return *(const bf16x8*)(base + row * 64 + c * 8);
}
__device__ __forceinline__ void stage_tile4(const u16* gbase, int K, char* lbase,
                                            int wave, int lane) {
#pragma unroll
  for (int i = 0; i < 4; ++i) {
    const int q = wave * 64 + lane + i * 256;
    const int r = q >> 3, c = (q & 7) ^ (r & 7);
    gl_lds16(gbase + (size_t)r * K + c * 8, lbase + i * 4096 + wave * 1024);
  }
}

// ---- BK=32 tiles ([rows][32], ((row>>1)&3) chunk-XOR swizzle; 2-way = free) -
__device__ __forceinline__ bf16x8 frag32(const u16* base, int row, int kchunk) {
  const int c = kchunk ^ ((row >> 1) & 3);
  return *(const bf16x8*)(base + row * 32 + c * 8);
}
__device__ __forceinline__ void stage32(const u16* gbase, int K, char* lbase,
                                        int wave, int lane) {
  const int q0 = wave * 64 + lane;                   // 128x32 = 512 chunks of 16B
  const int r0 = q0 >> 2, c0 = (q0 & 3) ^ ((r0 >> 1) & 3);
  gl_lds16(gbase + (size_t)r0 * K + c0 * 8, lbase + wave * 1024);
  const int q1 = q0 + 256;
  const int r1 = q1 >> 2, c1 = (q1 & 3) ^ ((r1 >> 1) & 3);
  gl_lds16(gbase + (size_t)r1 * K + c1 * 8, lbase + 4096 + wave * 1024);
}

// ---------------- cast fp32 -> bf16 (vectorized) ----------------
__global__ __launch_bounds__(256) void castk(const float* __restrict__ in,
                                             u16* __restrict__ out, int n) {
  int i = (blockIdx.x * 256 + threadIdx.x) * 8;
  if (i >= n) return;
  float4 a = *(const float4*)(in + i);
  float4 b = *(const float4*)(in + i + 4);
  u16x8 v;
  v[0] = f2b(a.x); v[1] = f2b(a.y); v[2] = f2b(a.z); v[3] = f2b(a.w);
  v[4] = f2b(b.x); v[5] = f2b(b.y); v[6] = f2b(b.z); v[7] = f2b(b.w);
  *(u16x8*)(out + i) = v;
}

// ---------------- GEMM1: 128x128, BK=32, dbuf, 1 sync/iter, 4 blocks/CU ------
__global__ __launch_bounds__(256, 4) void gemm_qkv(
    const u16* __restrict__ A, const u16* __restrict__ B,
    u16* __restrict__ Qo, u16* __restrict__ Ko, u16* __restrict__ Vo) {
  __shared__ u16 As[2][128 * 32];
  __shared__ u16 Bs[2][128 * 32];
  const int tid = threadIdx.x;
  const int lane = tid & 63, wave = tid >> 6;
  const int fr = lane & 15, fg = lane >> 4;
  const int wr = wave >> 1, wc = wave & 1;
  const int bid = blockIdx.x;
  const int bm = bid & 63, bn = bid >> 6;
  const int K = 1024;
  const u16* Ab = A + (size_t)bm * 128 * K;
  const u16* Bb = B + (size_t)bn * 128 * K;

  f32x4 acc[4][4] = {};

  stage32(Ab, K, (char*)&As[0][0], wave, lane);
  stage32(Bb, K, (char*)&Bs[0][0], wave, lane);
  __syncthreads();

  int cur = 0;
#pragma unroll 1
  for (int t = 0; t < 32; ++t) {
    if (t < 31) {
      stage32(Ab + (size_t)(t + 1) * 32, K, (char*)&As[cur ^ 1][0], wave, lane);
      stage32(Bb + (size_t)(t + 1) * 32, K, (char*)&Bs[cur ^ 1][0], wave, lane);
    }
    bf16x8 af[4], bfv[4];
#pragma unroll
    for (int mi = 0; mi < 4; ++mi)
      af[mi] = frag32(&As[cur][0], wr * 64 + mi * 16 + fr, fg);
#pragma unroll
    for (int ni = 0; ni < 4; ++ni)
      bfv[ni] = frag32(&Bs[cur][0], wc * 64 + ni * 16 + fr, fg);
#pragma unroll
    for (int mi = 0; mi < 4; ++mi)
#pragma unroll
      for (int ni = 0; ni < 4; ++ni)
        acc[mi][ni] = __builtin_amdgcn_mfma_f32_16x16x32_bf16(
            af[mi], bfv[ni], acc[mi][ni], 0, 0, 0);
    __syncthreads();
    cur ^= 1;
  }

  const int gr0 = bm * 128 + wr * 64;
  const int gc0 = bn * 128 + wc * 64;
#pragma unroll
  for (int mi = 0; mi < 4; ++mi) {
    const int rb = gr0 + mi * 16 + fg * 4;
    const int b = rb >> 10, t = rb & 1023;
#pragma unroll
    for (int ni = 0; ni < 4; ++ni) {
      const int c = gc0 + ni * 16 + fr;
      const int region = c >> 10, cc = c & 1023;
      const int h = cc >> 6, d = cc & 63;
      const size_t bh = (size_t)(b * 16 + h);
      if (region == 0) {
#pragma unroll
        for (int g = 0; g < 4; ++g)
          Qo[(bh * 1024 + t + g) * 64 + d] = f2b(acc[mi][ni][g] * QSCALE);
      } else if (region == 1) {
#pragma unroll
        for (int g = 0; g < 4; ++g)
          Ko[(bh * 1024 + t + g) * 64 + d] = f2b(acc[mi][ni][g]);
      } else {
        ushort4 pv;
        pv.x = f2b(acc[mi][ni][0]);
        pv.y = f2b(acc[mi][ni][1]);
        pv.z = f2b(acc[mi][ni][2]);
        pv.w = f2b(acc[mi][ni][3]);
        *(ushort4*)(Vo + (bh * 64 + d) * 1024 + t) = pv;   // V^T: [bh][d][t]
      }
    }
  }
}

// ---------------- GEMM2: 128x128, BK=64, dbuf, 1 sync/iter, swizzled --------
__global__ __launch_bounds__(256) void gemm_bt2(
    const u16* __restrict__ A, const u16* __restrict__ B,
    float* __restrict__ Co, const float* __restrict__ bias,
    const float* __restrict__ msk) {
  __shared__ u16 As[2][128 * 64];
  __shared__ u16 Bs[2][128 * 64];
  const int tid = threadIdx.x;
  const int lane = tid & 63, wave = tid >> 6;
  const int fr = lane & 15, fg = lane >> 4;
  const int wr = wave >> 1, wc = wave & 1;
  const int bid = blockIdx.x;
  const int bm = bid & 63, bn = bid >> 6;
  const int K = 1024, N = 1024;
  const u16* Ab = A + (size_t)bm * 128 * K;
  const u16* Bb = B + (size_t)bn * 128 * K;

  f32x4 acc[4][4] = {};

  stage_tile4(Ab, K, (char*)&As[0][0], wave, lane);
  stage_tile4(Bb, K, (char*)&Bs[0][0], wave, lane);
  __syncthreads();

  int cur = 0;
#pragma unroll 1
  for (int t = 0; t < 16; ++t) {
    if (t < 15) {
      stage_tile4(Ab + (size_t)(t + 1) * 64, K, (char*)&As[cur ^ 1][0], wave, lane);
      stage_tile4(Bb + (size_t)(t + 1) * 64, K, (char*)&Bs[cur ^ 1][0], wave, lane);
    }
    bf16x8 af[4][2], bfv[4][2];
#pragma unroll
    for (int mi = 0; mi < 4; ++mi)
#pragma unroll
      for (int kk = 0; kk < 2; ++kk)
        af[mi][kk] = frag(&As[cur][0], wr * 64 + mi * 16 + fr, kk * 4 + fg);
#pragma unroll
    for (int ni = 0; ni < 4; ++ni)
#pragma unroll
      for (int kk = 0; kk < 2; ++kk)
        bfv[ni][kk] = frag(&Bs[cur][0], wc * 64 + ni * 16 + fr, kk * 4 + fg);
#pragma unroll
    for (int mi = 0; mi < 4; ++mi)
#pragma unroll
      for (int ni = 0; ni < 4; ++ni)
#pragma unroll
        for (int kk = 0; kk < 2; ++kk)
          acc[mi][ni] = __builtin_amdgcn_mfma_f32_16x16x32_bf16(
              af[mi][kk], bfv[ni][kk], acc[mi][ni], 0, 0, 0);
    __syncthreads();
    cur ^= 1;
  }

  const int gr0 = bm * 128 + wr * 64;
  const int gc0 = bn * 128 + wc * 64;
#pragma unroll
  for (int mi = 0; mi < 4; ++mi) {
    const int rb = gr0 + mi * 16 + fg * 4;
#pragma unroll
    for (int ni = 0; ni < 4; ++ni) {
      const int c = gc0 + ni * 16 + fr;
      const float bo = bias[c];
#pragma unroll
      for (int g = 0; g < 4; ++g) {
        const int r = rb + g;
        Co[(size_t)r * N + c] = (acc[mi][ni][g] + bo) * msk[r];
      }
    }
  }
}

// ---------------- causal flash attention: paired q-tiles, uniform blocks ----
// grid 512 = 128 bh x 4 pairs. Block processes q-tile p then q-tile 7-p:
// (2p+2) + (16-2p) = 18 K-subtiles = 9 super-iters of 128 keys for EVERY block.
// Same-bh blocks (bid stride 128) land on the same XCD -> K/V L2-shared.
__global__ __launch_bounds__(256) void attnk(const u16* __restrict__ Qb,
                                             const u16* __restrict__ Kb,
                                             const u16* __restrict__ Vtb,
                                             const float* __restrict__ msk,
                                             u16* __restrict__ Ob) {
  __shared__ u16 Ks[2][2][64 * 64];   // [buf][sub][t][d], swizzled via source
  __shared__ u16 Vs[2][2][64 * 64];   // [buf][sub][d][t], swizzled via source
  __shared__ float mlds[1024];        // padding mask row for this b
  const int tid = threadIdx.x;
  const int lane = tid & 63, wave = tid >> 6;
  const int fr = lane & 15, fg = lane >> 4;
  const int bid = blockIdx.x;
  const int p = bid >> 7;             // pair index 0..3
  const int bh = bid & 127;
  const int b = bh >> 4, h = bh & 15;
  const int sa = p + 1;               // super-iters in tile a

  // preload padding mask row to LDS (256 threads x float4 = 4KB)
  ((float4*)mlds)[tid] = ((const float4*)(msk + (size_t)b * 1024))[tid];

  // bpermute source lanes for P redistribution:
  // target lane (fr,fg), word e2 of (mt,jc):
  //   value = pk[mt][jc*2 + (fg>>1)][e2&1] from lane fr + (fg&1)*32 + (e2&2 ? 16:0)
  const int src0 = fr + ((fg & 1) << 5);
  const int src1 = src0 + 16;

  // stage one 128-key super-tile (K + V^T sub-tiles) into buf
  auto stage2 = [&](int kb0, int buf) {
#pragma unroll
    for (int i = 0; i < 4; ++i) {
      const int qb_ = i * 256 + wave * 64;        // wave-uniform chunk base
      const int sub = qb_ >> 9;
      const int q2b = qb_ & 511;
      const int q2 = q2b + lane;
      const int r = q2 >> 3, c = (q2 & 7) ^ (r & 7);
      gl_lds16(Kb + ((size_t)bh * 1024 + (kb0 + sub) * 64 + r) * 64 + c * 8,
               (char*)&Ks[buf][sub][0] + q2b * 16);
      gl_lds16(Vtb + ((size_t)bh * 64 + r) * 1024 + (kb0 + sub) * 64 + c * 8,
               (char*)&Vs[buf][sub][0] + q2b * 16);
    }
  };

  int qw = p * 128 + wave * 32;
  bf16x8 qf[2][2];
  auto loadQ = [&]() {
#pragma unroll
    for (int ct = 0; ct < 2; ++ct)
#pragma unroll
      for (int kc = 0; kc < 2; ++kc)
        qf[ct][kc] = *(const bf16x8*)(Qb + ((size_t)bh * 1024 + qw + ct * 16 + fr) * 64 +
                                      kc * 32 + fg * 8);
  };
  loadQ();

  f32x4 o[2][4] = {};
  float mrun[2], lrun[2];
  mrun[0] = mrun[1] = -3.0e38f;
  lrun[0] = lrun[1] = 0.f;

  auto writeO = [&]() {
    float inv[2];
    inv[0] = 1.0f / lrun[0];
    inv[1] = 1.0f / lrun[1];
#pragma unroll
    for (int mt = 0; mt < 2; ++mt)
#pragma unroll
      for (int g = 0; g < 4; ++g) {
        const float invr = __shfl(inv[mt], fg * 4 + g);
        const int q = qw + mt * 16 + fg * 4 + g;
#pragma unroll
        for (int dt = 0; dt < 4; ++dt)
          Ob[((size_t)b * 1024 + q) * 1024 + h * 64 + dt * 16 + fr] =
              f2b(o[mt][dt][g] * invr);
      }
  };

  stage2(0, 0);   // prologue: super-tile 0 of tile a

#pragma unroll 1
  for (int s = 0; s < 9; ++s) {
    __syncthreads();   // stage(s) landed (implicit vmcnt0)
    if (s < 8) {       // prefetch next super-tile; hides under compute
      const int sn = s + 1;
      stage2(sn < sa ? 2 * sn : 2 * (sn - sa), sn & 1);
    }
    if (s == sa) {     // switch tile a -> tile b
      writeO();
      qw = (7 - p) * 128 + wave * 32;
      loadQ();
#pragma unroll
      for (int mt = 0; mt < 2; ++mt)
#pragma unroll
        for (int dt = 0; dt < 4; ++dt) o[mt][dt] = f32x4{0.f, 0.f, 0.f, 0.f};
      mrun[0] = mrun[1] = -3.0e38f;
      lrun[0] = lrun[1] = 0.f;
    }
    const int kb0 = (s < sa) ? 2 * s : 2 * (s - sa);

#pragma unroll
    for (int sub = 0; sub < 2; ++sub) {
      const int kb = kb0 + sub;
      if (kb * 64 > qw + 31) continue;   // above diagonal for this wave
      const u16* Kc = &Ks[s & 1][sub][0];
      const u16* Vc = &Vs[s & 1][sub][0];

      // --- S^T = K * Q^T : lane owns q-col = ct*16+fr, rows k = nt*16+fg*4+g
      f32x4 st[2][4];
      const f32x4 z = {0.f, 0.f, 0.f, 0.f};
#pragma unroll
      for (int nt = 0; nt < 4; ++nt) {
        const int krow = nt * 16 + fr;
        const int cb0r = (0 * 4 + fg) ^ (krow & 7);
        const int cb1r = (1 * 4 + fg) ^ (krow & 7);
        const bf16x8 kf0 = *(const bf16x8*)(Kc + krow * 64 + cb0r * 8);
        const bf16x8 kf1 = *(const bf16x8*)(Kc + krow * 64 + cb1r * 8);
#pragma unroll
        for (int ct = 0; ct < 2; ++ct) {
          st[ct][nt] = __builtin_amdgcn_mfma_f32_16x16x32_bf16(kf0, qf[ct][0], z, 0, 0, 0);
          st[ct][nt] = __builtin_amdgcn_mfma_f32_16x16x32_bf16(kf1, qf[ct][1], st[ct][nt], 0, 0, 0);
        }
      }

      // --- key padding mask values from LDS (applied post-exp2 as multiply)
      float kmv[4][4];
#pragma unroll
      for (int nt = 0; nt < 4; ++nt) {
        const float4 km4 = *(const float4*)(&mlds[kb * 64 + nt * 16 + fg * 4]);
        kmv[nt][0] = km4.x; kmv[nt][1] = km4.y; kmv[nt][2] = km4.z; kmv[nt][3] = km4.w;
      }

      // --- causal mask (diagonal tiles only)
      const bool edge = (kb * 64 + 63 > qw);
      if (edge) {
#pragma unroll
        for (int ct = 0; ct < 2; ++ct) {
          const int q = qw + ct * 16 + fr;
#pragma unroll
          for (int nt = 0; nt < 4; ++nt)
#pragma unroll
            for (int g = 0; g < 4; ++g) {
              const int j = kb * 64 + nt * 16 + fg * 4 + g;
              if (j > q) st[ct][nt][g] = -3.0e38f;
            }
        }
      }

      // --- online softmax with defer-max (T13, THR=8)
      float sc[2];
      int doR[2];
#pragma unroll
      for (int ct = 0; ct < 2; ++ct) {
        float mx = st[ct][0][0];
#pragma unroll
        for (int nt = 0; nt < 4; ++nt)
#pragma unroll
          for (int g = 0; g < 4; ++g) mx = fmaxf(mx, st[ct][nt][g]);
        mx = fmaxf(mx, __shfl_xor(mx, 16));
        mx = fmaxf(mx, __shfl_xor(mx, 32));
        float nm;
        if (__all(mx <= mrun[ct] + 8.f)) {
          nm = mrun[ct]; sc[ct] = 1.f; doR[ct] = 0;
        } else {
          nm = fmaxf(mrun[ct], mx);
          sc[ct] = exp2f(mrun[ct] - nm);
          mrun[ct] = nm; doR[ct] = 1;
        }
        float rs = 0.f;
#pragma unroll
        for (int nt = 0; nt < 4; ++nt)
#pragma unroll
          for (int g = 0; g < 4; ++g) {
            const float pq = exp2f(st[ct][nt][g] - nm) * kmv[nt][g];
            st[ct][nt][g] = pq;
            rs += pq;
          }
        rs += __shfl_xor(rs, 16);
        rs += __shfl_xor(rs, 32);
        lrun[ct] = doR[ct] ? (lrun[ct] * sc[ct] + rs) : (lrun[ct] + rs);
      }

      // --- pack P pairs to bf16x2 words (v_cvt_pk_bf16_f32)
      int pk[2][4][2];
#pragma unroll
      for (int ct = 0; ct < 2; ++ct)
#pragma unroll
        for (int nt = 0; nt < 4; ++nt)
#pragma unroll
          for (int hh = 0; hh < 2; ++hh) {
            bf16x2 tp;
            tp[0] = (bf16)st[ct][nt][2 * hh];
            tp[1] = (bf16)st[ct][nt][2 * hh + 1];
            pk[ct][nt][hh] = __builtin_bit_cast(int, tp);
          }

      // --- redistribute to PV A-fragments via bpermute (no LDS)
      bf16x8 pa[2][2];
#pragma unroll
      for (int mt = 0; mt < 2; ++mt)
#pragma unroll
        for (int jc = 0; jc < 2; ++jc) {
          int w[4];
#pragma unroll
          for (int e2 = 0; e2 < 4; ++e2) {
            const int sl = (e2 & 2) ? src1 : src0;
            const int lo = __shfl(pk[mt][jc * 2 + 0][e2 & 1], sl);
            const int hi = __shfl(pk[mt][jc * 2 + 1][e2 & 1], sl);
            w[e2] = (fg & 2) ? hi : lo;
          }
          int4 wi = {w[0], w[1], w[2], w[3]};
          pa[mt][jc] = __builtin_bit_cast(bf16x8, wi);
        }

      // --- rescale O only when max grew (wave-uniform branch)
#pragma unroll
      for (int mt = 0; mt < 2; ++mt)
        if (doR[mt]) {
#pragma unroll
          for (int g = 0; g < 4; ++g) {
            const float scr = __shfl(sc[mt], fg * 4 + g);
#pragma unroll
            for (int dt = 0; dt < 4; ++dt) o[mt][dt][g] *= scr;
          }
        }

      // --- PV: O[q][d] += P[q][k] * V[k][d]
#pragma unroll
      for (int jc = 0; jc < 2; ++jc)
#pragma unroll
        for (int dt = 0; dt < 4; ++dt) {
          const int vrow = dt * 16 + fr;
          const int cb = (jc * 4 + fg) ^ (vrow & 7);
          const bf16x8 vf = *(const bf16x8*)(Vc + vrow * 64 + cb * 8);
#pragma unroll
          for (int mt = 0; mt < 2; ++mt)
            o[mt][dt] = __builtin_amdgcn_mfma_f32_16x16x32_bf16(pa[mt][jc], vf, o[mt][dt], 0, 0, 0);
        }
    }
  }

  writeO();   // tile b epilogue
}

// ---------------- launcher ----------------
extern "C" void kernel_launch(void* const* d_in, const int* in_sizes, int n_in,
                              void* d_out, int out_size, void* d_ws, size_t ws_size,
                              hipStream_t stream) {
  (void)in_sizes; (void)n_in; (void)out_size; (void)ws_size;
  const float* x = (const float*)d_in[0];
  const float* m = (const float*)d_in[1];
  const float* w_qkv = (const float*)d_in[2];
  const float* w_out = (const float*)d_in[3];
  const float* b_out = (const float*)d_in[4];
  float* out = (float*)d_out;

  char* ws = (char*)d_ws;
  const size_t MB = 1u << 20;
  u16* Xb    = (u16*)(ws + 0);         // 16MB, reused as Ob after GEMM1
  u16* Wqkvb = (u16*)(ws + 16 * MB);   // 6MB
  u16* Woutb = (u16*)(ws + 22 * MB);   // 2MB
  u16* Qb    = (u16*)(ws + 24 * MB);   // 16MB
  u16* Kb    = (u16*)(ws + 40 * MB);   // 16MB
  u16* Vtb   = (u16*)(ws + 56 * MB);   // 16MB  -> total 72MB
  u16* Ob    = Xb;                      // alias: X dead after GEMM1

  // casts
  castk<<<4096, 256, 0, stream>>>(x, Xb, 8 * 1024 * 1024);
  castk<<<1536, 256, 0, stream>>>(w_qkv, Wqkvb, 3072 * 1024);
  castk<<<512, 256, 0, stream>>>(w_out, Woutb, 1024 * 1024);

  // GEMM1: qkv = X @ Wqkv^T (128^2, BK=32 dbuf, 4 blocks/CU TLP)
  gemm_qkv<<<1536, 256, 0, stream>>>(Xb, Wqkvb, Qb, Kb, Vtb);

  // flash attention (paired q-tiles: every block = 18 K-subtiles, zero tail)
  attnk<<<512, 256, 0, stream>>>(Qb, Kb, Vtb, m, Ob);

  // GEMM2: out = (O @ Wout^T + b_out) * m  (128^2, BK=64 dbuf)
  gemm_bt2<<<512, 256, 0, stream>>>(Ob, Woutb, out, b_out, m);
}

// Round 10
// 163.025 us; speedup vs baseline: 1.0735x; 1.0214x over previous
//
#include <hip/hip_runtime.h>
#include <cstdint>
#include <cstddef>

typedef unsigned short u16;
typedef __bf16 bf16;
typedef bf16 __attribute__((ext_vector_type(2))) bf16x2;
typedef bf16 __attribute__((ext_vector_type(8))) bf16x8;
typedef float __attribute__((ext_vector_type(4))) f32x4;
typedef u16 __attribute__((ext_vector_type(8))) u16x8;

// SCALE * log2(e) folded into Q so softmax runs in exp2 domain
#define QSCALE 0.18033688011112042f

__device__ __forceinline__ u16 f2b(float x) {
  unsigned u = __float_as_uint(x);
  unsigned r = (u + 0x7fffu + ((u >> 16) & 1u)) >> 16;   // RNE
  return (u16)r;
}

__device__ __forceinline__ void gl_lds16(const void* g, void* lds) {
  __builtin_amdgcn_global_load_lds(
      (const __attribute__((address_space(1))) unsigned int*)g,
      (__attribute__((address_space(3))) unsigned int*)lds, 16, 0, 0);
}

// ---- BK=64 tiles ([rows][64], (row&7) chunk-XOR swizzle) --------------------
__device__ __forceinline__ bf16x8 frag(const u16* base, int row, int kchunk) {
  const int c = kchunk ^ (row & 7);
  return *(const bf16x8*)(base + row * 64 + c * 8);
}
__device__ __forceinline__ void stage_tile4(const u16* gbase, int K, char* lbase,
                                            int wave, int lane) {
#pragma unroll
  for (int i = 0; i < 4; ++i) {
    const int q = wave * 64 + lane + i * 256;
    const int r = q >> 3, c = (q & 7) ^ (r & 7);
    gl_lds16(gbase + (size_t)r * K + c * 8, lbase + i * 4096 + wave * 1024);
  }
}

// ---- BK=32 tiles ([rows][32], ((row>>1)&3) chunk-XOR swizzle; 2-way = free) -
__device__ __forceinline__ bf16x8 frag32(const u16* base, int row, int kchunk) {
  const int c = kchunk ^ ((row >> 1) & 3);
  return *(const bf16x8*)(base + row * 32 + c * 8);
}
__device__ __forceinline__ void stage32(const u16* gbase, int K, char* lbase,
                                        int wave, int lane) {
  const int q0 = wave * 64 + lane;                   // 128x32 = 512 chunks of 16B
  const int r0 = q0 >> 2, c0 = (q0 & 3) ^ ((r0 >> 1) & 3);
  gl_lds16(gbase + (size_t)r0 * K + c0 * 8, lbase + wave * 1024);
  const int q1 = q0 + 256;
  const int r1 = q1 >> 2, c1 = (q1 & 3) ^ ((r1 >> 1) & 3);
  gl_lds16(gbase + (size_t)r1 * K + c1 * 8, lbase + 4096 + wave * 1024);
}

// ---------------- cast fp32 -> bf16 (vectorized) ----------------
__global__ __launch_bounds__(256) void castk(const float* __restrict__ in,
                                             u16* __restrict__ out, int n) {
  int i = (blockIdx.x * 256 + threadIdx.x) * 8;
  if (i >= n) return;
  float4 a = *(const float4*)(in + i);
  float4 b = *(const float4*)(in + i + 4);
  u16x8 v;
  v[0] = f2b(a.x); v[1] = f2b(a.y); v[2] = f2b(a.z); v[3] = f2b(a.w);
  v[4] = f2b(b.x); v[5] = f2b(b.y); v[6] = f2b(b.z); v[7] = f2b(b.w);
  *(u16x8*)(out + i) = v;
}

// ---------------- GEMM1: 128x128, BK=32, dbuf, 1 sync/iter, 4 blocks/CU ------
__global__ __launch_bounds__(256, 4) void gemm_qkv(
    const u16* __restrict__ A, const u16* __restrict__ B,
    u16* __restrict__ Qo, u16* __restrict__ Ko, u16* __restrict__ Vo) {
  __shared__ u16 As[2][128 * 32];
  __shared__ u16 Bs[2][128 * 32];
  const int tid = threadIdx.x;
  const int lane = tid & 63, wave = tid >> 6;
  const int fr = lane & 15, fg = lane >> 4;
  const int wr = wave >> 1, wc = wave & 1;
  const int bid = blockIdx.x;
  const int bm = bid & 63, bn = bid >> 6;
  const int K = 1024;
  const u16* Ab = A + (size_t)bm * 128 * K;
  const u16* Bb = B + (size_t)bn * 128 * K;

  f32x4 acc[4][4] = {};

  stage32(Ab, K, (char*)&As[0][0], wave, lane);
  stage32(Bb, K, (char*)&Bs[0][0], wave, lane);
  __syncthreads();

  int cur = 0;
#pragma unroll 1
  for (int t = 0; t < 32; ++t) {
    if (t < 31) {
      stage32(Ab + (size_t)(t + 1) * 32, K, (char*)&As[cur ^ 1][0], wave, lane);
      stage32(Bb + (size_t)(t + 1) * 32, K, (char*)&Bs[cur ^ 1][0], wave, lane);
    }
    bf16x8 af[4], bfv[4];
#pragma unroll
    for (int mi = 0; mi < 4; ++mi)
      af[mi] = frag32(&As[cur][0], wr * 64 + mi * 16 + fr, fg);
#pragma unroll
    for (int ni = 0; ni < 4; ++ni)
      bfv[ni] = frag32(&Bs[cur][0], wc * 64 + ni * 16 + fr, fg);
#pragma unroll
    for (int mi = 0; mi < 4; ++mi)
#pragma unroll
      for (int ni = 0; ni < 4; ++ni)
        acc[mi][ni] = __builtin_amdgcn_mfma_f32_16x16x32_bf16(
            af[mi], bfv[ni], acc[mi][ni], 0, 0, 0);
    __syncthreads();
    cur ^= 1;
  }

  const int gr0 = bm * 128 + wr * 64;
  const int gc0 = bn * 128 + wc * 64;
#pragma unroll
  for (int mi = 0; mi < 4; ++mi) {
    const int rb = gr0 + mi * 16 + fg * 4;
    const int b = rb >> 10, t = rb & 1023;
#pragma unroll
    for (int ni = 0; ni < 4; ++ni) {
      const int c = gc0 + ni * 16 + fr;
      const int region = c >> 10, cc = c & 1023;
      const int h = cc >> 6, d = cc & 63;
      const size_t bh = (size_t)(b * 16 + h);
      if (region == 0) {
#pragma unroll
        for (int g = 0; g < 4; ++g)
          Qo[(bh * 1024 + t + g) * 64 + d] = f2b(acc[mi][ni][g] * QSCALE);
      } else if (region == 1) {
#pragma unroll
        for (int g = 0; g < 4; ++g)
          Ko[(bh * 1024 + t + g) * 64 + d] = f2b(acc[mi][ni][g]);
      } else {
        ushort4 pv;
        pv.x = f2b(acc[mi][ni][0]);
        pv.y = f2b(acc[mi][ni][1]);
        pv.z = f2b(acc[mi][ni][2]);
        pv.w = f2b(acc[mi][ni][3]);
        *(ushort4*)(Vo + (bh * 64 + d) * 1024 + t) = pv;   // V^T: [bh][d][t]
      }
    }
  }
}

// ---------------- GEMM2: 128x128, BK=64, dbuf, 1 sync/iter, swizzled --------
__global__ __launch_bounds__(256) void gemm_bt2(
    const u16* __restrict__ A, const u16* __restrict__ B,
    float* __restrict__ Co, const float* __restrict__ bias,
    const float* __restrict__ msk) {
  __shared__ u16 As[2][128 * 64];
  __shared__ u16 Bs[2][128 * 64];
  const int tid = threadIdx.x;
  const int lane = tid & 63, wave = tid >> 6;
  const int fr = lane & 15, fg = lane >> 4;
  const int wr = wave >> 1, wc = wave & 1;
  const int bid = blockIdx.x;
  const int bm = bid & 63, bn = bid >> 6;
  const int K = 1024, N = 1024;
  const u16* Ab = A + (size_t)bm * 128 * K;
  const u16* Bb = B + (size_t)bn * 128 * K;

  f32x4 acc[4][4] = {};

  stage_tile4(Ab, K, (char*)&As[0][0], wave, lane);
  stage_tile4(Bb, K, (char*)&Bs[0][0], wave, lane);
  __syncthreads();

  int cur = 0;
#pragma unroll 1
  for (int t = 0; t < 16; ++t) {
    if (t < 15) {
      stage_tile4(Ab + (size_t)(t + 1) * 64, K, (char*)&As[cur ^ 1][0], wave, lane);
      stage_tile4(Bb + (size_t)(t + 1) * 64, K, (char*)&Bs[cur ^ 1][0], wave, lane);
    }
    bf16x8 af[4][2], bfv[4][2];
#pragma unroll
    for (int mi = 0; mi < 4; ++mi)
#pragma unroll
      for (int kk = 0; kk < 2; ++kk)
        af[mi][kk] = frag(&As[cur][0], wr * 64 + mi * 16 + fr, kk * 4 + fg);
#pragma unroll
    for (int ni = 0; ni < 4; ++ni)
#pragma unroll
      for (int kk = 0; kk < 2; ++kk)
        bfv[ni][kk] = frag(&Bs[cur][0], wc * 64 + ni * 16 + fr, kk * 4 + fg);
#pragma unroll
    for (int mi = 0; mi < 4; ++mi)
#pragma unroll
      for (int ni = 0; ni < 4; ++ni)
#pragma unroll
        for (int kk = 0; kk < 2; ++kk)
          acc[mi][ni] = __builtin_amdgcn_mfma_f32_16x16x32_bf16(
              af[mi][kk], bfv[ni][kk], acc[mi][ni], 0, 0, 0);
    __syncthreads();
    cur ^= 1;
  }

  const int gr0 = bm * 128 + wr * 64;
  const int gc0 = bn * 128 + wc * 64;
#pragma unroll
  for (int mi = 0; mi < 4; ++mi) {
    const int rb = gr0 + mi * 16 + fg * 4;
#pragma unroll
    for (int ni = 0; ni < 4; ++ni) {
      const int c = gc0 + ni * 16 + fr;
      const float bo = bias[c];
#pragma unroll
      for (int g = 0; g < 4; ++g) {
        const int r = rb + g;
        Co[(size_t)r * N + c] = (acc[mi][ni][g] + bo) * msk[r];
      }
    }
  }
}

// ---------------- causal flash attention: 64-row strips, 4 blocks/CU --------
// grid 1024 = 128 bh x 8 pairs (s, 15-s). Block: strip s (s+1 subs) then strip
// 15-s (16-s subs) = 17 subs for EVERY block; every wave works every sub.
// LDS 36KB -> 4 blocks/CU = 4 waves/SIMD co-resident (latency-filling TLP).
__global__ __launch_bounds__(256) void attnk(const u16* __restrict__ Qb,
                                             const u16* __restrict__ Kb,
                                             const u16* __restrict__ Vtb,
                                             const float* __restrict__ msk,
                                             u16* __restrict__ Ob) {
  __shared__ u16 Ks[2][64 * 64];     // [buf][t][d], swizzled via staged source
  __shared__ u16 Vs[2][64 * 64];     // [buf][d][t], swizzled via staged source
  __shared__ float mlds[1024];       // padding mask row for this b
  const int tid = threadIdx.x;
  const int lane = tid & 63, wave = tid >> 6;
  const int fr = lane & 15, fg = lane >> 4;
  const int bid = blockIdx.x;
  const int s = bid >> 7;            // pair index 0..7
  const int bh = bid & 127;
  const int b = bh >> 4, h = bh & 15;

  // preload padding mask row to LDS (256 threads x float4 = 4KB)
  ((float4*)mlds)[tid] = ((const float4*)(msk + (size_t)b * 1024))[tid];

  // stage one 64-key sub-tile (K + V^T) into buf
  auto stage = [&](int kb, int buf) {
    const int q0 = wave * 64 + lane;
    const int r0 = q0 >> 3, c0 = (q0 & 7) ^ (r0 & 7);
    gl_lds16(Kb + ((size_t)bh * 1024 + kb * 64 + r0) * 64 + c0 * 8,
             (char*)&Ks[buf][0] + wave * 1024);
    gl_lds16(Vtb + ((size_t)bh * 64 + r0) * 1024 + kb * 64 + c0 * 8,
             (char*)&Vs[buf][0] + wave * 1024);
    const int q1 = q0 + 256;
    const int r1 = q1 >> 3, c1 = (q1 & 7) ^ (r1 & 7);
    gl_lds16(Kb + ((size_t)bh * 1024 + kb * 64 + r1) * 64 + c1 * 8,
             (char*)&Ks[buf][0] + 4096 + wave * 1024);
    gl_lds16(Vtb + ((size_t)bh * 64 + r1) * 1024 + kb * 64 + c1 * 8,
             (char*)&Vs[buf][0] + 4096 + wave * 1024);
  };

  int qw = s * 64 + wave * 16;       // wave's 16 q-rows
  bf16x8 qf[2];
  auto loadQ = [&]() {
#pragma unroll
    for (int kc = 0; kc < 2; ++kc)
      qf[kc] = *(const bf16x8*)(Qb + ((size_t)bh * 1024 + qw + fr) * 64 +
                                kc * 32 + fg * 8);
  };
  loadQ();

  f32x4 o[4] = {};
  float mrun = -3.0e38f, lrun = 0.f;

  auto writeO = [&]() {
    const float inv = 1.0f / lrun;
#pragma unroll
    for (int g = 0; g < 4; ++g) {
      const float invr = __shfl(inv, fg * 4 + g);
      const int q = qw + fg * 4 + g;
#pragma unroll
      for (int dt = 0; dt < 4; ++dt)
        Ob[((size_t)b * 1024 + q) * 1024 + h * 64 + dt * 16 + fr] =
            f2b(o[dt][g] * invr);
    }
  };

  stage(0, 0);   // prologue: strip A, kb=0

#pragma unroll 1
  for (int it = 0; it <= 16; ++it) {   // 17 subs, uniform for every block
    __syncthreads();                   // stage(it) landed (implicit vmcnt0)
    if (it < 16) {                     // prefetch next sub; hides under compute
      const int nkb = (it + 1 <= s) ? (it + 1) : (it - s);
      stage(nkb, (it + 1) & 1);
    }
    if (it == s + 1) {                 // switch strip A -> strip B
      writeO();
      qw = (15 - s) * 64 + wave * 16;
      loadQ();
#pragma unroll
      for (int dt = 0; dt < 4; ++dt) o[dt] = f32x4{0.f, 0.f, 0.f, 0.f};
      mrun = -3.0e38f;
      lrun = 0.f;
    }
    const int kb = (it <= s) ? it : (it - s - 1);
    const u16* Kc = &Ks[it & 1][0];
    const u16* Vc = &Vs[it & 1][0];

    // --- S^T = K * Q^T : lane owns q-row = qw+fr, k = nt*16 + fg*4 + g ---
    f32x4 st[4];
    const f32x4 z = {0.f, 0.f, 0.f, 0.f};
#pragma unroll
    for (int nt = 0; nt < 4; ++nt) {
      const int krow = nt * 16 + fr;
      const int cb0r = (0 * 4 + fg) ^ (krow & 7);
      const int cb1r = (1 * 4 + fg) ^ (krow & 7);
      const bf16x8 kf0 = *(const bf16x8*)(Kc + krow * 64 + cb0r * 8);
      const bf16x8 kf1 = *(const bf16x8*)(Kc + krow * 64 + cb1r * 8);
      st[nt] = __builtin_amdgcn_mfma_f32_16x16x32_bf16(kf0, qf[0], z, 0, 0, 0);
      st[nt] = __builtin_amdgcn_mfma_f32_16x16x32_bf16(kf1, qf[1], st[nt], 0, 0, 0);
    }

    // --- key padding mask values from LDS (applied post-exp2 as multiply) ---
    float kmv[4][4];
#pragma unroll
    for (int nt = 0; nt < 4; ++nt) {
      const float4 km4 = *(const float4*)(&mlds[kb * 64 + nt * 16 + fg * 4]);
      kmv[nt][0] = km4.x; kmv[nt][1] = km4.y; kmv[nt][2] = km4.z; kmv[nt][3] = km4.w;
    }

    // --- causal mask: needed unless ALL keys <= MIN q-row of the wave (qw).
    // (Round-9 bug: tested against qw+15, leaving wave 3's diagonal unmasked.)
    if (kb * 64 + 63 > qw) {
      const int q = qw + fr;
#pragma unroll
      for (int nt = 0; nt < 4; ++nt)
#pragma unroll
        for (int g = 0; g < 4; ++g) {
          const int j = kb * 64 + nt * 16 + fg * 4 + g;
          if (j > q) st[nt][g] = -3.0e38f;
        }
    }

    // --- online softmax with defer-max (T13, THR=8) ---
    float mx = st[0][0];
#pragma unroll
    for (int nt = 0; nt < 4; ++nt)
#pragma unroll
      for (int g = 0; g < 4; ++g) mx = fmaxf(mx, st[nt][g]);
    mx = fmaxf(mx, __shfl_xor(mx, 16));
    mx = fmaxf(mx, __shfl_xor(mx, 32));
    float nm, sc;
    int doR;
    if (__all(mx <= mrun + 8.f)) {
      nm = mrun; sc = 1.f; doR = 0;
    } else {
      nm = fmaxf(mrun, mx);
      sc = exp2f(mrun - nm);
      mrun = nm; doR = 1;
    }
    float rs = 0.f;
#pragma unroll
    for (int nt = 0; nt < 4; ++nt)
#pragma unroll
      for (int g = 0; g < 4; ++g) {
        const float pq = exp2f(st[nt][g] - nm) * kmv[nt][g];
        st[nt][g] = pq;
        rs += pq;
      }
    rs += __shfl_xor(rs, 16);
    rs += __shfl_xor(rs, 32);
    lrun = doR ? (lrun * sc + rs) : (lrun + rs);

    // --- pack P pairs to bf16x2 words (v_cvt_pk_bf16_f32) ---
    int pk[4][2];
#pragma unroll
    for (int nt = 0; nt < 4; ++nt)
#pragma unroll
      for (int hh = 0; hh < 2; ++hh) {
        bf16x2 tp;
        tp[0] = (bf16)st[nt][2 * hh];
        tp[1] = (bf16)st[nt][2 * hh + 1];
        pk[nt][hh] = __builtin_bit_cast(int, tp);
      }

    // --- redistribute to PV A-fragments via shfl (no LDS round-trip) ---
    // target lane (fr,fg) dword e2 of pa[jc] = P[qw+fr][jc*32+fg*8+2e2(+1)]
    //   = pk[jc*2 + (fg>>1)][e2&1] read from lane fr + (fg&1)*32 + ((e2&2)?16:0).
    // shfl both nt-halves with WAVE-UNIFORM register indices, select per-lane
    // (lane-varying index inside __shfl reads the SOURCE lane's index — r8 bug).
    bf16x8 pa[2];
#pragma unroll
    for (int jc = 0; jc < 2; ++jc) {
      int w[4];
#pragma unroll
      for (int e2 = 0; e2 < 4; ++e2) {
        const int sl = fr + ((fg & 1) << 5) + ((e2 & 2) ? 16 : 0);
        const int lo = __shfl(pk[jc * 2 + 0][e2 & 1], sl);
        const int hi = __shfl(pk[jc * 2 + 1][e2 & 1], sl);
        w[e2] = (fg & 2) ? hi : lo;
      }
      int4 wi = {w[0], w[1], w[2], w[3]};
      pa[jc] = __builtin_bit_cast(bf16x8, wi);
    }

    // --- rescale O only when max grew (wave-uniform branch) ---
    if (doR) {
#pragma unroll
      for (int g = 0; g < 4; ++g) {
        const float scr = __shfl(sc, fg * 4 + g);
#pragma unroll
        for (int dt = 0; dt < 4; ++dt) o[dt][g] *= scr;
      }
    }

    // --- PV: O[q][d] += P[q][k] * V[k][d] ---
#pragma unroll
    for (int jc = 0; jc < 2; ++jc)
#pragma unroll
      for (int dt = 0; dt < 4; ++dt) {
        const int vrow = dt * 16 + fr;
        const int cb = (jc * 4 + fg) ^ (vrow & 7);
        const bf16x8 vf = *(const bf16x8*)(Vc + vrow * 64 + cb * 8);
        o[dt] = __builtin_amdgcn_mfma_f32_16x16x32_bf16(pa[jc], vf, o[dt], 0, 0, 0);
      }
  }

  writeO();   // strip B epilogue
}

// ---------------- launcher ----------------
extern "C" void kernel_launch(void* const* d_in, const int* in_sizes, int n_in,
                              void* d_out, int out_size, void* d_ws, size_t ws_size,
                              hipStream_t stream) {
  (void)in_sizes; (void)n_in; (void)out_size; (void)ws_size;
  const float* x = (const float*)d_in[0];
  const float* m = (const float*)d_in[1];
  const float* w_qkv = (const float*)d_in[2];
  const float* w_out = (const float*)d_in[3];
  const float* b_out = (const float*)d_in[4];
  float* out = (float*)d_out;

  char* ws = (char*)d_ws;
  const size_t MB = 1u << 20;
  u16* Xb    = (u16*)(ws + 0);         // 16MB, reused as Ob after GEMM1
  u16* Wqkvb = (u16*)(ws + 16 * MB);   // 6MB
  u16* Woutb = (u16*)(ws + 22 * MB);   // 2MB
  u16* Qb    = (u16*)(ws + 24 * MB);   // 16MB
  u16* Kb    = (u16*)(ws + 40 * MB);   // 16MB
  u16* Vtb   = (u16*)(ws + 56 * MB);   // 16MB  -> total 72MB
  u16* Ob    = Xb;                      // alias: X dead after GEMM1

  // casts
  castk<<<4096, 256, 0, stream>>>(x, Xb, 8 * 1024 * 1024);
  castk<<<1536, 256, 0, stream>>>(w_qkv, Wqkvb, 3072 * 1024);
  castk<<<512, 256, 0, stream>>>(w_out, Woutb, 1024 * 1024);

  // GEMM1: qkv = X @ Wqkv^T (128^2, BK=32 dbuf, 4 blocks/CU TLP)
  gemm_qkv<<<1536, 256, 0, stream>>>(Xb, Wqkvb, Qb, Kb, Vtb);

  // flash attention (64-row strips paired: 17 subs/block, 4 blocks/CU)
  attnk<<<1024, 256, 0, stream>>>(Qb, Kb, Vtb, m, Ob);

  // GEMM2: out = (O @ Wout^T + b_out) * m  (128^2, BK=64 dbuf)
  gemm_bt2<<<512, 256, 0, stream>>>(Ob, Woutb, out, b_out, m);
}

// Round 11
// 158.327 us; speedup vs baseline: 1.1053x; 1.0297x over previous
//
#include <hip/hip_runtime.h>
#include <cstdint>
#include <cstddef>

typedef unsigned short u16;
typedef __bf16 bf16;
typedef bf16 __attribute__((ext_vector_type(2))) bf16x2;
typedef bf16 __attribute__((ext_vector_type(8))) bf16x8;
typedef float __attribute__((ext_vector_type(4))) f32x4;
typedef u16 __attribute__((ext_vector_type(8))) u16x8;

// SCALE * log2(e) folded into Q so softmax runs in exp2 domain
#define QSCALE 0.18033688011112042f

__device__ __forceinline__ u16 f2b(float x) {
  unsigned u = __float_as_uint(x);
  unsigned r = (u + 0x7fffu + ((u >> 16) & 1u)) >> 16;   // RNE
  return (u16)r;
}

__device__ __forceinline__ void gl_lds16(const void* g, void* lds) {
  __builtin_amdgcn_global_load_lds(
      (const __attribute__((address_space(1))) unsigned int*)g,
      (__attribute__((address_space(3))) unsigned int*)lds, 16, 0, 0);
}

// ---- BK=64 tiles ([rows][64], (row&7) chunk-XOR swizzle) --------------------
__device__ __forceinline__ bf16x8 frag(const u16* base, int row, int kchunk) {
  const int c = kchunk ^ (row & 7);
  return *(const bf16x8*)(base + row * 64 + c * 8);
}
__device__ __forceinline__ void stage_tile4(const u16* gbase, int K, char* lbase,
                                            int wave, int lane) {
#pragma unroll
  for (int i = 0; i < 4; ++i) {
    const int q = wave * 64 + lane + i * 256;
    const int r = q >> 3, c = (q & 7) ^ (r & 7);
    gl_lds16(gbase + (size_t)r * K + c * 8, lbase + i * 4096 + wave * 1024);
  }
}

// ---- BK=32 tiles ([rows][32], ((row>>1)&3) chunk-XOR swizzle; 2-way = free) -
__device__ __forceinline__ bf16x8 frag32(const u16* base, int row, int kchunk) {
  const int c = kchunk ^ ((row >> 1) & 3);
  return *(const bf16x8*)(base + row * 32 + c * 8);
}
__device__ __forceinline__ void stage32(const u16* gbase, int K, char* lbase,
                                        int wave, int lane) {
  const int q0 = wave * 64 + lane;                   // 128x32 = 512 chunks of 16B
  const int r0 = q0 >> 2, c0 = (q0 & 3) ^ ((r0 >> 1) & 3);
  gl_lds16(gbase + (size_t)r0 * K + c0 * 8, lbase + wave * 1024);
  const int q1 = q0 + 256;
  const int r1 = q1 >> 2, c1 = (q1 & 3) ^ ((r1 >> 1) & 3);
  gl_lds16(gbase + (size_t)r1 * K + c1 * 8, lbase + 4096 + wave * 1024);
}

// ---------------- cast fp32 -> bf16 (vectorized) ----------------
__global__ __launch_bounds__(256) void castk(const float* __restrict__ in,
                                             u16* __restrict__ out, int n) {
  int i = (blockIdx.x * 256 + threadIdx.x) * 8;
  if (i >= n) return;
  float4 a = *(const float4*)(in + i);
  float4 b = *(const float4*)(in + i + 4);
  u16x8 v;
  v[0] = f2b(a.x); v[1] = f2b(a.y); v[2] = f2b(a.z); v[3] = f2b(a.w);
  v[4] = f2b(b.x); v[5] = f2b(b.y); v[6] = f2b(b.z); v[7] = f2b(b.w);
  *(u16x8*)(out + i) = v;
}

// ---------------- GEMM1: 128x128, BK=32, TRIPLE-buffer, counted vmcnt --------
// 2-ahead prefetch: stage(t+2) issued each iter; barrier waits only the OLDEST
// stage (vmcnt(4)) so the newest 4 loads span two compute phases (T4 pattern).
// LDS 48KB -> 3 blocks/CU.
__global__ __launch_bounds__(256, 3) void gemm_qkv(
    const u16* __restrict__ A, const u16* __restrict__ B,
    u16* __restrict__ Qo, u16* __restrict__ Ko, u16* __restrict__ Vo) {
  __shared__ u16 As[3][128 * 32];
  __shared__ u16 Bs[3][128 * 32];
  const int tid = threadIdx.x;
  const int lane = tid & 63, wave = tid >> 6;
  const int fr = lane & 15, fg = lane >> 4;
  const int wr = wave >> 1, wc = wave & 1;
  const int bid = blockIdx.x;
  const int bm = bid & 63, bn = bid >> 6;
  const int K = 1024;
  const u16* Ab = A + (size_t)bm * 128 * K;
  const u16* Bb = B + (size_t)bn * 128 * K;

  f32x4 acc[4][4] = {};

  // prologue: tiles 0,1 in flight (8 outstanding VMEM/thread)
  stage32(Ab, K, (char*)&As[0][0], wave, lane);
  stage32(Bb, K, (char*)&Bs[0][0], wave, lane);
  stage32(Ab + 32, K, (char*)&As[1][0], wave, lane);
  stage32(Bb + 32, K, (char*)&Bs[1][0], wave, lane);

  int cur = 0;
#pragma unroll 1
  for (int t = 0; t < 32; ++t) {
    // wait tile t (oldest 4 loads); tile t+1's 4 stay in flight; drain LDS reads
    if (t == 31) asm volatile("s_waitcnt vmcnt(0) lgkmcnt(0)" ::: "memory");
    else         asm volatile("s_waitcnt vmcnt(4) lgkmcnt(0)" ::: "memory");
    __builtin_amdgcn_s_barrier();   // tile t LDS-complete block-wide; tile t-1 readers done
    __builtin_amdgcn_sched_barrier(0);
    if (t + 2 < 32) {               // 2-ahead prefetch into the buffer tile t-1 used
      int stg = cur + 2; if (stg >= 3) stg -= 3;
      stage32(Ab + (size_t)(t + 2) * 32, K, (char*)&As[stg][0], wave, lane);
      stage32(Bb + (size_t)(t + 2) * 32, K, (char*)&Bs[stg][0], wave, lane);
    }
    bf16x8 af[4], bfv[4];
#pragma unroll
    for (int mi = 0; mi < 4; ++mi)
      af[mi] = frag32(&As[cur][0], wr * 64 + mi * 16 + fr, fg);
#pragma unroll
    for (int ni = 0; ni < 4; ++ni)
      bfv[ni] = frag32(&Bs[cur][0], wc * 64 + ni * 16 + fr, fg);
#pragma unroll
    for (int mi = 0; mi < 4; ++mi)
#pragma unroll
      for (int ni = 0; ni < 4; ++ni)
        acc[mi][ni] = __builtin_amdgcn_mfma_f32_16x16x32_bf16(
            af[mi], bfv[ni], acc[mi][ni], 0, 0, 0);
    cur = (cur + 1 == 3) ? 0 : cur + 1;
  }

  const int gr0 = bm * 128 + wr * 64;
  const int gc0 = bn * 128 + wc * 64;
#pragma unroll
  for (int mi = 0; mi < 4; ++mi) {
    const int rb = gr0 + mi * 16 + fg * 4;
    const int b = rb >> 10, t = rb & 1023;
#pragma unroll
    for (int ni = 0; ni < 4; ++ni) {
      const int c = gc0 + ni * 16 + fr;
      const int region = c >> 10, cc = c & 1023;
      const int h = cc >> 6, d = cc & 63;
      const size_t bh = (size_t)(b * 16 + h);
      if (region == 0) {
#pragma unroll
        for (int g = 0; g < 4; ++g)
          Qo[(bh * 1024 + t + g) * 64 + d] = f2b(acc[mi][ni][g] * QSCALE);
      } else if (region == 1) {
#pragma unroll
        for (int g = 0; g < 4; ++g)
          Ko[(bh * 1024 + t + g) * 64 + d] = f2b(acc[mi][ni][g]);
      } else {
        ushort4 pv;
        pv.x = f2b(acc[mi][ni][0]);
        pv.y = f2b(acc[mi][ni][1]);
        pv.z = f2b(acc[mi][ni][2]);
        pv.w = f2b(acc[mi][ni][3]);
        *(ushort4*)(Vo + (bh * 64 + d) * 1024 + t) = pv;   // V^T: [bh][d][t]
      }
    }
  }
}

// ---------------- GEMM2: 128x128, BK=64, dbuf, 1 sync/iter, swizzled --------
__global__ __launch_bounds__(256) void gemm_bt2(
    const u16* __restrict__ A, const u16* __restrict__ B,
    float* __restrict__ Co, const float* __restrict__ bias,
    const float* __restrict__ msk) {
  __shared__ u16 As[2][128 * 64];
  __shared__ u16 Bs[2][128 * 64];
  const int tid = threadIdx.x;
  const int lane = tid & 63, wave = tid >> 6;
  const int fr = lane & 15, fg = lane >> 4;
  const int wr = wave >> 1, wc = wave & 1;
  const int bid = blockIdx.x;
  const int bm = bid & 63, bn = bid >> 6;
  const int K = 1024, N = 1024;
  const u16* Ab = A + (size_t)bm * 128 * K;
  const u16* Bb = B + (size_t)bn * 128 * K;

  f32x4 acc[4][4] = {};

  stage_tile4(Ab, K, (char*)&As[0][0], wave, lane);
  stage_tile4(Bb, K, (char*)&Bs[0][0], wave, lane);
  __syncthreads();

  int cur = 0;
#pragma unroll 1
  for (int t = 0; t < 16; ++t) {
    if (t < 15) {
      stage_tile4(Ab + (size_t)(t + 1) * 64, K, (char*)&As[cur ^ 1][0], wave, lane);
      stage_tile4(Bb + (size_t)(t + 1) * 64, K, (char*)&Bs[cur ^ 1][0], wave, lane);
    }
    bf16x8 af[4][2], bfv[4][2];
#pragma unroll
    for (int mi = 0; mi < 4; ++mi)
#pragma unroll
      for (int kk = 0; kk < 2; ++kk)
        af[mi][kk] = frag(&As[cur][0], wr * 64 + mi * 16 + fr, kk * 4 + fg);
#pragma unroll
    for (int ni = 0; ni < 4; ++ni)
#pragma unroll
      for (int kk = 0; kk < 2; ++kk)
        bfv[ni][kk] = frag(&Bs[cur][0], wc * 64 + ni * 16 + fr, kk * 4 + fg);
#pragma unroll
    for (int mi = 0; mi < 4; ++mi)
#pragma unroll
      for (int ni = 0; ni < 4; ++ni)
#pragma unroll
        for (int kk = 0; kk < 2; ++kk)
          acc[mi][ni] = __builtin_amdgcn_mfma_f32_16x16x32_bf16(
              af[mi][kk], bfv[ni][kk], acc[mi][ni], 0, 0, 0);
    __syncthreads();
    cur ^= 1;
  }

  const int gr0 = bm * 128 + wr * 64;
  const int gc0 = bn * 128 + wc * 64;
#pragma unroll
  for (int mi = 0; mi < 4; ++mi) {
    const int rb = gr0 + mi * 16 + fg * 4;
#pragma unroll
    for (int ni = 0; ni < 4; ++ni) {
      const int c = gc0 + ni * 16 + fr;
      const float bo = bias[c];
#pragma unroll
      for (int g = 0; g < 4; ++g) {
        const int r = rb + g;
        Co[(size_t)r * N + c] = (acc[mi][ni][g] + bo) * msk[r];
      }
    }
  }
}

// ---------------- causal flash attention: 64-row strips, 4 blocks/CU --------
__global__ __launch_bounds__(256) void attnk(const u16* __restrict__ Qb,
                                             const u16* __restrict__ Kb,
                                             const u16* __restrict__ Vtb,
                                             const float* __restrict__ msk,
                                             u16* __restrict__ Ob) {
  __shared__ u16 Ks[2][64 * 64];     // [buf][t][d], swizzled via staged source
  __shared__ u16 Vs[2][64 * 64];     // [buf][d][t], swizzled via staged source
  __shared__ float mlds[1024];       // padding mask row for this b
  const int tid = threadIdx.x;
  const int lane = tid & 63, wave = tid >> 6;
  const int fr = lane & 15, fg = lane >> 4;
  const int bid = blockIdx.x;
  const int s = bid >> 7;            // pair index 0..7
  const int bh = bid & 127;
  const int b = bh >> 4, h = bh & 15;

  ((float4*)mlds)[tid] = ((const float4*)(msk + (size_t)b * 1024))[tid];

  auto stage = [&](int kb, int buf) {
    const int q0 = wave * 64 + lane;
    const int r0 = q0 >> 3, c0 = (q0 & 7) ^ (r0 & 7);
    gl_lds16(Kb + ((size_t)bh * 1024 + kb * 64 + r0) * 64 + c0 * 8,
             (char*)&Ks[buf][0] + wave * 1024);
    gl_lds16(Vtb + ((size_t)bh * 64 + r0) * 1024 + kb * 64 + c0 * 8,
             (char*)&Vs[buf][0] + wave * 1024);
    const int q1 = q0 + 256;
    const int r1 = q1 >> 3, c1 = (q1 & 7) ^ (r1 & 7);
    gl_lds16(Kb + ((size_t)bh * 1024 + kb * 64 + r1) * 64 + c1 * 8,
             (char*)&Ks[buf][0] + 4096 + wave * 1024);
    gl_lds16(Vtb + ((size_t)bh * 64 + r1) * 1024 + kb * 64 + c1 * 8,
             (char*)&Vs[buf][0] + 4096 + wave * 1024);
  };

  int qw = s * 64 + wave * 16;       // wave's 16 q-rows
  bf16x8 qf[2];
  auto loadQ = [&]() {
#pragma unroll
    for (int kc = 0; kc < 2; ++kc)
      qf[kc] = *(const bf16x8*)(Qb + ((size_t)bh * 1024 + qw + fr) * 64 +
                                kc * 32 + fg * 8);
  };
  loadQ();

  f32x4 o[4] = {};
  float mrun = -3.0e38f, lrun = 0.f;

  auto writeO = [&]() {
    const float inv = 1.0f / lrun;
#pragma unroll
    for (int g = 0; g < 4; ++g) {
      const float invr = __shfl(inv, fg * 4 + g);
      const int q = qw + fg * 4 + g;
#pragma unroll
      for (int dt = 0; dt < 4; ++dt)
        Ob[((size_t)b * 1024 + q) * 1024 + h * 64 + dt * 16 + fr] =
            f2b(o[dt][g] * invr);
    }
  };

  stage(0, 0);   // prologue: strip A, kb=0

#pragma unroll 1
  for (int it = 0; it <= 16; ++it) {   // 17 subs, uniform for every block
    __syncthreads();                   // stage(it) landed (implicit vmcnt0)
    if (it < 16) {                     // prefetch next sub; hides under compute
      const int nkb = (it + 1 <= s) ? (it + 1) : (it - s);
      stage(nkb, (it + 1) & 1);
    }
    if (it == s + 1) {                 // switch strip A -> strip B
      writeO();
      qw = (15 - s) * 64 + wave * 16;
      loadQ();
#pragma unroll
      for (int dt = 0; dt < 4; ++dt) o[dt] = f32x4{0.f, 0.f, 0.f, 0.f};
      mrun = -3.0e38f;
      lrun = 0.f;
    }
    const int kb = (it <= s) ? it : (it - s - 1);
    const u16* Kc = &Ks[it & 1][0];
    const u16* Vc = &Vs[it & 1][0];

    // --- S^T = K * Q^T : lane owns q-row = qw+fr, k = nt*16 + fg*4 + g ---
    f32x4 st[4];
    const f32x4 z = {0.f, 0.f, 0.f, 0.f};
#pragma unroll
    for (int nt = 0; nt < 4; ++nt) {
      const int krow = nt * 16 + fr;
      const int cb0r = (0 * 4 + fg) ^ (krow & 7);
      const int cb1r = (1 * 4 + fg) ^ (krow & 7);
      const bf16x8 kf0 = *(const bf16x8*)(Kc + krow * 64 + cb0r * 8);
      const bf16x8 kf1 = *(const bf16x8*)(Kc + krow * 64 + cb1r * 8);
      st[nt] = __builtin_amdgcn_mfma_f32_16x16x32_bf16(kf0, qf[0], z, 0, 0, 0);
      st[nt] = __builtin_amdgcn_mfma_f32_16x16x32_bf16(kf1, qf[1], st[nt], 0, 0, 0);
    }

    // --- key padding mask values from LDS (applied post-exp2 as multiply) ---
    float kmv[4][4];
#pragma unroll
    for (int nt = 0; nt < 4; ++nt) {
      const float4 km4 = *(const float4*)(&mlds[kb * 64 + nt * 16 + fg * 4]);
      kmv[nt][0] = km4.x; kmv[nt][1] = km4.y; kmv[nt][2] = km4.z; kmv[nt][3] = km4.w;
    }

    // --- causal mask: needed unless ALL keys <= MIN q-row of the wave (qw) ---
    if (kb * 64 + 63 > qw) {
      const int q = qw + fr;
#pragma unroll
      for (int nt = 0; nt < 4; ++nt)
#pragma unroll
        for (int g = 0; g < 4; ++g) {
          const int j = kb * 64 + nt * 16 + fg * 4 + g;
          if (j > q) st[nt][g] = -3.0e38f;
        }
    }

    // --- online softmax with defer-max (T13, THR=8) ---
    float mx = st[0][0];
#pragma unroll
    for (int nt = 0; nt < 4; ++nt)
#pragma unroll
      for (int g = 0; g < 4; ++g) mx = fmaxf(mx, st[nt][g]);
    mx = fmaxf(mx, __shfl_xor(mx, 16));
    mx = fmaxf(mx, __shfl_xor(mx, 32));
    float nm, sc;
    int doR;
    if (__all(mx <= mrun + 8.f)) {
      nm = mrun; sc = 1.f; doR = 0;
    } else {
      nm = fmaxf(mrun, mx);
      sc = exp2f(mrun - nm);
      mrun = nm; doR = 1;
    }
    float rs = 0.f;
#pragma unroll
    for (int nt = 0; nt < 4; ++nt)
#pragma unroll
      for (int g = 0; g < 4; ++g) {
        const float pq = exp2f(st[nt][g] - nm) * kmv[nt][g];
        st[nt][g] = pq;
        rs += pq;
      }
    rs += __shfl_xor(rs, 16);
    rs += __shfl_xor(rs, 32);
    lrun = doR ? (lrun * sc + rs) : (lrun + rs);

    // --- pack P pairs to bf16x2 words (v_cvt_pk_bf16_f32) ---
    int pk[4][2];
#pragma unroll
    for (int nt = 0; nt < 4; ++nt)
#pragma unroll
      for (int hh = 0; hh < 2; ++hh) {
        bf16x2 tp;
        tp[0] = (bf16)st[nt][2 * hh];
        tp[1] = (bf16)st[nt][2 * hh + 1];
        pk[nt][hh] = __builtin_bit_cast(int, tp);
      }

    // --- redistribute to PV A-fragments via shfl (wave-uniform reg indices,
    //     per-lane select; lane-varying index inside __shfl was the r8 bug) ---
    bf16x8 pa[2];
#pragma unroll
    for (int jc = 0; jc < 2; ++jc) {
      int w[4];
#pragma unroll
      for (int e2 = 0; e2 < 4; ++e2) {
        const int sl = fr + ((fg & 1) << 5) + ((e2 & 2) ? 16 : 0);
        const int lo = __shfl(pk[jc * 2 + 0][e2 & 1], sl);
        const int hi = __shfl(pk[jc * 2 + 1][e2 & 1], sl);
        w[e2] = (fg & 2) ? hi : lo;
      }
      int4 wi = {w[0], w[1], w[2], w[3]};
      pa[jc] = __builtin_bit_cast(bf16x8, wi);
    }

    // --- rescale O only when max grew (wave-uniform branch) ---
    if (doR) {
#pragma unroll
      for (int g = 0; g < 4; ++g) {
        const float scr = __shfl(sc, fg * 4 + g);
#pragma unroll
        for (int dt = 0; dt < 4; ++dt) o[dt][g] *= scr;
      }
    }

    // --- PV: O[q][d] += P[q][k] * V[k][d] ---
#pragma unroll
    for (int jc = 0; jc < 2; ++jc)
#pragma unroll
      for (int dt = 0; dt < 4; ++dt) {
        const int vrow = dt * 16 + fr;
        const int cb = (jc * 4 + fg) ^ (vrow & 7);
        const bf16x8 vf = *(const bf16x8*)(Vc + vrow * 64 + cb * 8);
        o[dt] = __builtin_amdgcn_mfma_f32_16x16x32_bf16(pa[jc], vf, o[dt], 0, 0, 0);
      }
  }

  writeO();   // strip B epilogue
}

// ---------------- launcher ----------------
extern "C" void kernel_launch(void* const* d_in, const int* in_sizes, int n_in,
                              void* d_out, int out_size, void* d_ws, size_t ws_size,
                              hipStream_t stream) {
  (void)in_sizes; (void)n_in; (void)out_size; (void)ws_size;
  const float* x = (const float*)d_in[0];
  const float* m = (const float*)d_in[1];
  const float* w_qkv = (const float*)d_in[2];
  const float* w_out = (const float*)d_in[3];
  const float* b_out = (const float*)d_in[4];
  float* out = (float*)d_out;

  char* ws = (char*)d_ws;
  const size_t MB = 1u << 20;
  u16* Xb    = (u16*)(ws + 0);         // 16MB, reused as Ob after GEMM1
  u16* Wqkvb = (u16*)(ws + 16 * MB);   // 6MB
  u16* Woutb = (u16*)(ws + 22 * MB);   // 2MB
  u16* Qb    = (u16*)(ws + 24 * MB);   // 16MB
  u16* Kb    = (u16*)(ws + 40 * MB);   // 16MB
  u16* Vtb   = (u16*)(ws + 56 * MB);   // 16MB  -> total 72MB
  u16* Ob    = Xb;                      // alias: X dead after GEMM1

  // casts
  castk<<<4096, 256, 0, stream>>>(x, Xb, 8 * 1024 * 1024);
  castk<<<1536, 256, 0, stream>>>(w_qkv, Wqkvb, 3072 * 1024);
  castk<<<512, 256, 0, stream>>>(w_out, Woutb, 1024 * 1024);

  // GEMM1: qkv = X @ Wqkv^T (128^2, BK=32 tribuf, counted vmcnt, 3 blocks/CU)
  gemm_qkv<<<1536, 256, 0, stream>>>(Xb, Wqkvb, Qb, Kb, Vtb);

  // flash attention (64-row strips paired: 17 subs/block, 4 blocks/CU)
  attnk<<<1024, 256, 0, stream>>>(Qb, Kb, Vtb, m, Ob);

  // GEMM2: out = (O @ Wout^T + b_out) * m  (128^2, BK=64 dbuf)
  gemm_bt2<<<512, 256, 0, stream>>>(Ob, Woutb, out, b_out, m);
}